// Round 22
// baseline (255.544 us; speedup 1.0000x reference)
//
#include <hip/hip_runtime.h>
#include <hip/hip_bf16.h>

// ---------------------------------------------------------------------------
// Conformer block: bf16-MFMA GEMMs (XCD-swizzled, counted-vmcnt; small GEMMs
// 64x128x64 XOR-swizzled 8-wave; QKV 128x128x32 8-wave; pw1 128x256x32) +
// SPLIT-KV bf16-MFMA flash attention (128 q-rows x KV-half per block, 8 waves,
// single-buffered K/V 2-barrier tiles -> 36.9KB LDS -> 4 blocks/CU, exact
// online-softmax combine pass) + LDS-tiled depthwise conv with fused BN stats
// + wave-per-row LN + mega-prep.
// B=8, T=1024, D=512, HID=1024, C=1024, K=31, H=8, dh=64.  M = B*T = 8192.
// ---------------------------------------------------------------------------

#define M_ROWS 8192

using bf16x8 = __attribute__((ext_vector_type(8))) short;
using f32x4  = __attribute__((ext_vector_type(4))) float;
using s8v    = __attribute__((ext_vector_type(8))) short;
using s4v    = __attribute__((ext_vector_type(4))) short;

__device__ __forceinline__ float sigmoid_(float v) { return 1.f / (1.f + expf(-v)); }

__device__ __forceinline__ float bf2f(short s) {
  return __uint_as_float(((unsigned)(unsigned short)s) << 16);
}
__device__ __forceinline__ short f2bf(float f) {
  __hip_bfloat16 h = __float2bfloat16(f);
  return *reinterpret_cast<short*>(&h);
}

__device__ __forceinline__ void gl16(const void* g, void* l) {
  __builtin_amdgcn_global_load_lds((const __attribute__((address_space(1))) void*)g,
                                   (__attribute__((address_space(3))) void*)l, 16, 0, 0);
}

// ---------------------------------------------------------------------------
// bf16 MFMA GEMM: outb[M,N] = epi(A[M,K] @ Bt[N,K]^T + bias).
// BK=32: linear LDS. BK=64: XOR-swizzled (linear LDS dest + inverse-swizzled
// GLOBAL source + same XOR on frag read). Counted-vmcnt 2-buffer K-loop.
// EPI: 1 swish->bf16 | 2 resb+acc+bias->bf16 | 3 resb+0.5*(acc+bias)->bf16
//      4 QKV: table-RoPE q/k ->bf16 (B,H,T,64); v->bf16 (B,H,64,T), vstg
//             aliased on smem | 6 pw1+GLU (packed weights)
// ---------------------------------------------------------------------------
template <int BM, int BN, int BK, int EPI, int THREADS>
__global__ __launch_bounds__(THREADS) void mgemm(
    const short* __restrict__ A, const short* __restrict__ Bt,
    const float* __restrict__ bias, const float* __restrict__ res,
    const short* __restrict__ resb, short* __restrict__ outb, int M, int N, int K) {
  constexpr int NW = THREADS / 64;
  constexpr int WR = BM / 64;
  constexpr int WC = NW / WR;
  constexpr int NF = BN / (16 * WC);
  constexpr int CPW = BN / WC;
  constexpr int KH = BK / 32;
  constexpr int RPP = THREADS / (BK / 8);
  constexpr int APASS = BM / RPP;
  constexpr int BPASS = BN / RPP;
  constexpr int LPS = APASS + BPASS;
  __shared__ __align__(16) short smem[2 * BM * BK + 2 * BN * BK];
  short* As0 = smem;
  short* Bs0 = smem + 2 * BM * BK;
  const int tid = threadIdx.x;
  const int lane = tid & 63, wid = tid >> 6;
  const int wr = wid / WC, wc = wid % WC;
  const int nbx = gridDim.x;
  const int nwg = nbx * gridDim.y;
  int id = blockIdx.y * nbx + blockIdx.x;
  id = (id & 7) * (nwg >> 3) + (id >> 3);
  const int bm = (id / nbx) * BM;
  const int bn = (id % nbx) * BN;
  f32x4 acc[4][NF];
#pragma unroll
  for (int m = 0; m < 4; ++m)
#pragma unroll
    for (int n = 0; n < NF; ++n) acc[m][n] = (f32x4){0.f, 0.f, 0.f, 0.f};
  const short* Ablk = A + (size_t)bm * K;
  const short* Bblk = Bt + (size_t)bn * K;
  const int jl = tid & (BK / 8 - 1);
  const int r0 = tid / (BK / 8);
  const int ks = ((BK == 64) ? (jl ^ (r0 & 7)) : jl) << 3;
#define STAGE(buf, k0)                                                                 \
  do {                                                                                 \
    _Pragma("unroll")                                                                  \
    for (int p = 0; p < APASS; ++p)                                                    \
      gl16(Ablk + (size_t)(r0 + p * RPP) * K + (k0) + ks,                              \
           (char*)(As0 + (buf) * BM * BK) + p * (THREADS * 16) + wid * 1024);          \
    _Pragma("unroll")                                                                  \
    for (int p = 0; p < BPASS; ++p)                                                    \
      gl16(Bblk + (size_t)(r0 + p * RPP) * K + (k0) + ks,                              \
           (char*)(Bs0 + (buf) * BN * BK) + p * (THREADS * 16) + wid * 1024);          \
  } while (0)

  STAGE(0, 0);
  STAGE(1, BK);
  const int NS = K / BK;
  const int fr = lane & 15, fg = lane >> 4;
  const int arow = wr * 64 + fr;
  const int brow = wc * CPW + fr;
  for (int i = 0; i < NS; ++i) {
    if (i + 1 < NS) {
      if constexpr (LPS == 6)      asm volatile("s_waitcnt vmcnt(6)" ::: "memory");
      else if constexpr (LPS == 4) asm volatile("s_waitcnt vmcnt(4)" ::: "memory");
      else if constexpr (LPS == 3) asm volatile("s_waitcnt vmcnt(3)" ::: "memory");
      else                         asm volatile("s_waitcnt vmcnt(2)" ::: "memory");
    } else {
      asm volatile("s_waitcnt vmcnt(0)" ::: "memory");
    }
    __builtin_amdgcn_s_barrier();
    asm volatile("" ::: "memory");
    const int cur = i & 1;
    bf16x8 af[KH][4], bfr[KH][NF];
#pragma unroll
    for (int kk = 0; kk < KH; ++kk) {
      const int cx = (BK == 64) ? (((((kk << 2) + fg)) ^ (fr & 7)) << 3)
                                : ((fg << 3) + kk * 32);
#pragma unroll
      for (int m = 0; m < 4; ++m)
        af[kk][m] = *reinterpret_cast<const bf16x8*>(
            &As0[cur * BM * BK + (arow + m * 16) * BK + cx]);
#pragma unroll
      for (int n = 0; n < NF; ++n)
        bfr[kk][n] = *reinterpret_cast<const bf16x8*>(
            &Bs0[cur * BN * BK + (brow + n * 16) * BK + cx]);
    }
    asm volatile("s_waitcnt lgkmcnt(0)" ::: "memory");
    __builtin_amdgcn_s_barrier();
    if ((i + 2) * BK < K) STAGE(cur, (i + 2) * BK);
#pragma unroll
    for (int kk = 0; kk < KH; ++kk)
#pragma unroll
      for (int m = 0; m < 4; ++m)
#pragma unroll
        for (int n = 0; n < NF; ++n)
          acc[m][n] = __builtin_amdgcn_mfma_f32_16x16x32_bf16(af[kk][m], bfr[kk][n],
                                                              acc[m][n], 0, 0, 0);
  }
#undef STAGE
  const int orow0 = bm + wr * 64 + ((lane >> 4) << 2);
  const int ocol0 = bn + wc * CPW + fr;

  if constexpr (EPI == 4) {
    const int sel = bn >> 9;
    const float2* tbl = (const float2*)res;  // [1024][32] (cos,sin)
    if (sel == 2) {
      short* vstg = smem;  // aliases smem; first use behind a barrier
      const int b_ = bm >> 10, t0v = bm & 1023;
      const int hb = (bn & 511) >> 6;
#pragma unroll
      for (int pass = 0; pass < 2; ++pass) {
        __syncthreads();
        if (((wc * CPW) >> 6) == pass) {
          const int dlb = (wc * CPW) & 63;
#pragma unroll
          for (int m = 0; m < 4; ++m) {
            const int rl = wr * 64 + ((lane >> 4) << 2) + m * 16;
#pragma unroll
            for (int n = 0; n < NF; ++n) {
              const int dl = dlb + n * 16 + fr;
              const float bv = bias[bn + pass * 64 + dl];
#pragma unroll
              for (int r = 0; r < 4; ++r)
                vstg[dl * 132 + rl + r] = f2bf(acc[m][n][r] + bv);
            }
          }
        }
        __syncthreads();
        for (int c = tid; c < 1024; c += THREADS) {
          const int d = c >> 4, t8 = (c & 15) << 3;
          const s8v val = *reinterpret_cast<const s8v*>(&vstg[d * 132 + t8]);
          *reinterpret_cast<s8v*>(
              &outb[(size_t)8388608 + (((size_t)((b_ << 3) + hb + pass)) << 16) +
                    ((size_t)d << 10) + t0v + t8]) = val;
        }
      }
    } else {
      const float qsc = (sel == 0) ? 0.04419417382415922f : 1.f;  // 1/sqrt(512)
#pragma unroll
      for (int n = 0; n < NF; ++n) {
        const int col = ocol0 + n * 16;
        const int h = (col >> 6) & 7, d = col & 63;
        const int p = d >> 1;
        const float bv = bias[col];
#pragma unroll
        for (int m = 0; m < 4; ++m) {
#pragma unroll
          for (int r = 0; r < 4; ++r) {
            const int row = orow0 + m * 16 + r;
            const int b_ = row >> 10, t_ = row & 1023;
            const int pos = (sel == 0) ? h : t_;
            const float2 cs = tbl[pos * 32 + p];
            float vv = acc[m][n][r] + bv;
            const float pv = __shfl_xor(vv, 1);
            float o = ((lane & 1) == 0) ? (vv * cs.x - pv * cs.y) : (vv * cs.x + pv * cs.y);
            outb[(size_t)sel * 4194304 + (((size_t)((b_ << 3) + h)) << 16) + ((size_t)t_ << 6) + d] =
                f2bf(o * qsc);
          }
        }
      }
    }
  } else if constexpr (EPI == 6) {
#pragma unroll
    for (int m = 0; m < 4; ++m) {
#pragma unroll
      for (int np = 0; np < NF / 2; ++np) {
        const int colbase = bn + wc * CPW + ((2 * np) << 4);
        const int j = colbase >> 7;
        const int u = (colbase >> 5) & 3;
        const int gc = (j << 6) + (u << 4) + fr;
        const float ba = bias[gc];
        const float bg = bias[1024 + gc];
#pragma unroll
        for (int r = 0; r < 4; ++r) {
          const int row = orow0 + m * 16 + r;
          const float a = acc[m][2 * np][r] + ba;
          const float g = acc[m][2 * np + 1][r] + bg;
          outb[(size_t)row * 1024 + gc] = f2bf(a * sigmoid_(g));
        }
      }
    }
  } else {
#pragma unroll
    for (int m = 0; m < 4; ++m) {
#pragma unroll
      for (int n = 0; n < NF; ++n) {
        const int col = ocol0 + n * 16;
        const float bv = bias[col];
#pragma unroll
        for (int r = 0; r < 4; ++r) {
          const int row = orow0 + m * 16 + r;
          float v = acc[m][n][r] + bv;
          if constexpr (EPI == 1) {
            v = v * sigmoid_(v);
          } else if constexpr (EPI == 2) {
            v += bf2f(resb[(size_t)row * N + col]);
          } else if constexpr (EPI == 3) {
            v = bf2f(resb[(size_t)row * N + col]) + 0.5f * v;
          }
          outb[(size_t)row * N + col] = f2bf(v);
        }
      }
    }
  }
}

// ---------------------------------------------------------------------------
// MEGA-PREP: all weight casts/transposes/packs + bias concat + rope table.
// ---------------------------------------------------------------------------
__device__ __forceinline__ void dev_cast8(const float* in, short* out, int i) {
  const float4 a = *reinterpret_cast<const float4*>(&in[(size_t)i * 8]);
  const float4 b = *reinterpret_cast<const float4*>(&in[(size_t)i * 8 + 4]);
  s8v o = { f2bf(a.x), f2bf(a.y), f2bf(a.z), f2bf(a.w),
            f2bf(b.x), f2bf(b.y), f2bf(b.z), f2bf(b.w) };
  *reinterpret_cast<s8v*>(&out[(size_t)i * 8]) = o;
}

__global__ __launch_bounds__(256) void prep_kernel(
    const float* __restrict__ x, short* __restrict__ xb,
    const float* __restrict__ f1w1, short* __restrict__ wf1w1,
    const float* __restrict__ f1w2, short* __restrict__ wf1w2,
    const float* __restrict__ wq, const float* __restrict__ wk,
    const float* __restrict__ wv, short* __restrict__ wqkv,
    const float* __restrict__ wo, short* __restrict__ wwo,
    const float* __restrict__ pw1, short* __restrict__ wpw1,
    const float* __restrict__ pw2, short* __restrict__ wpw2,
    const float* __restrict__ f2w1, short* __restrict__ wf2w1,
    const float* __restrict__ f2w2, short* __restrict__ wf2w2,
    const float* __restrict__ bq, const float* __restrict__ bk,
    const float* __restrict__ bv, float* __restrict__ bqkv,
    float* __restrict__ rtbl) {
  __shared__ float t[32][33];
  const int blk = blockIdx.x, tid = threadIdx.x;
  const float* tin = nullptr;
  short* tout = nullptr;
  int tK = 0, tN = 0, tr = 0, tnbx = 0;
  if (blk < 2048) {
    dev_cast8(x, xb, blk * 256 + tid);
    return;
  } else if (blk < 2560) { tin = f1w1; tout = wf1w1; tK = 512; tN = 1024; tr = blk - 2048; tnbx = 32; }
  else if (blk < 3072)   { tin = f1w2; tout = wf1w2; tK = 1024; tN = 512; tr = blk - 2560; tnbx = 16; }
  else if (blk < 3328)   { tin = wq; tout = wqkv; tK = 512; tN = 512; tr = blk - 3072; tnbx = 16; }
  else if (blk < 3584)   { tin = wk; tout = wqkv + 512 * 512; tK = 512; tN = 512; tr = blk - 3328; tnbx = 16; }
  else if (blk < 3840)   { tin = wv; tout = wqkv + 1024 * 512; tK = 512; tN = 512; tr = blk - 3584; tnbx = 16; }
  else if (blk < 4096)   { tin = wo; tout = wwo; tK = 512; tN = 512; tr = blk - 3840; tnbx = 16; }
  else if (blk < 4608) {
    const int idx = (blk - 4096) * 256 + tid;
    const int pc = idx >> 6, kk = (idx & 63) << 3;
    const int j = pc >> 7, s = (pc >> 4) & 7, fr = pc & 15;
    const int oc = ((s & 1) << 10) + (j << 6) + ((s >> 1) << 4) + fr;
    const float4 a = *reinterpret_cast<const float4*>(&pw1[(size_t)oc * 512 + kk]);
    const float4 b = *reinterpret_cast<const float4*>(&pw1[(size_t)oc * 512 + kk + 4]);
    s8v o = { f2bf(a.x), f2bf(a.y), f2bf(a.z), f2bf(a.w),
              f2bf(b.x), f2bf(b.y), f2bf(b.z), f2bf(b.w) };
    *reinterpret_cast<s8v*>(&wpw1[(size_t)pc * 512 + kk]) = o;
    return;
  } else if (blk < 4864) {
    dev_cast8(pw2, wpw2, (blk - 4608) * 256 + tid);
    return;
  } else if (blk < 5376) { tin = f2w1; tout = wf2w1; tK = 512; tN = 1024; tr = blk - 4864; tnbx = 32; }
  else if (blk < 5888)   { tin = f2w2; tout = wf2w2; tK = 1024; tN = 512; tr = blk - 5376; tnbx = 16; }
  else if (blk < 6016) {
    const int i = (blk - 5888) * 256 + tid;  // 32768
    const int tt = i >> 5, p = i & 31;
    const float inv = exp2f(-(float)p * 0.41524101186092f);
    float s, c;
    sincosf((float)tt * inv, &s, &c);
    rtbl[i * 2] = c;
    rtbl[i * 2 + 1] = s;
    return;
  } else {
    const int i = (blk - 6016) * 256 + tid;
    if (i < 1536) bqkv[i] = i < 512 ? bq[i] : (i < 1024 ? bk[i - 512] : bv[i - 1024]);
    return;
  }
  const int n0 = (tr % tnbx) << 5, k0 = (tr / tnbx) << 5;
  const int tx = tid & 31, ty = tid >> 5;
  for (int r = ty; r < 32; r += 8) t[r][tx] = tin[(size_t)(k0 + r) * tN + n0 + tx];
  __syncthreads();
  for (int r = ty; r < 32; r += 8) tout[(size_t)(n0 + r) * tK + k0 + tx] = f2bf(t[tx][r]);
}

// ---------------------------------------------------------------------------
// LayerNorm over last dim (512), bf16 input. One WAVE per row (4 rows/block).
// ---------------------------------------------------------------------------
template <typename OT>
__global__ __launch_bounds__(256) void ln_kernel(
    const short* __restrict__ in, const float* __restrict__ g,
    const float* __restrict__ b, OT* __restrict__ out) {
  const int tid = threadIdx.x, lane = tid & 63;
  const size_t row = ((size_t)blockIdx.x << 2) + (tid >> 6);
  const int c0 = lane << 3;
  const s8v v = *reinterpret_cast<const s8v*>(&in[(row << 9) + c0]);
  float f[8];
  float s = 0.f;
#pragma unroll
  for (int j = 0; j < 8; ++j) { f[j] = bf2f(v[j]); s += f[j]; }
  for (int o = 32; o; o >>= 1) s += __shfl_xor(s, o);
  const float mean = s * (1.f / 512.f);
  float d[8];
  float q = 0.f;
#pragma unroll
  for (int j = 0; j < 8; ++j) { d[j] = f[j] - mean; q = fmaf(d[j], d[j], q); }
  for (int o = 32; o; o >>= 1) q += __shfl_xor(q, o);
  const float inv = rsqrtf(q * (1.f / 512.f) + 1e-5f);
  const float4 g0 = *reinterpret_cast<const float4*>(&g[c0]);
  const float4 g1 = *reinterpret_cast<const float4*>(&g[c0 + 4]);
  const float4 b0 = *reinterpret_cast<const float4*>(&b[c0]);
  const float4 b1 = *reinterpret_cast<const float4*>(&b[c0 + 4]);
  const float gg[8] = {g0.x, g0.y, g0.z, g0.w, g1.x, g1.y, g1.z, g1.w};
  const float bb[8] = {b0.x, b0.y, b0.z, b0.w, b1.x, b1.y, b1.z, b1.w};
  if constexpr (sizeof(OT) == 2) {
    s8v o;
#pragma unroll
    for (int j = 0; j < 8; ++j) o[j] = f2bf(d[j] * inv * gg[j] + bb[j]);
    *reinterpret_cast<s8v*>(&out[(row << 9) + c0]) = o;
  } else {
    float4 o0, o1;
    o0.x = d[0] * inv * gg[0] + bb[0]; o0.y = d[1] * inv * gg[1] + bb[1];
    o0.z = d[2] * inv * gg[2] + bb[2]; o0.w = d[3] * inv * gg[3] + bb[3];
    o1.x = d[4] * inv * gg[4] + bb[4]; o1.y = d[5] * inv * gg[5] + bb[5];
    o1.z = d[6] * inv * gg[6] + bb[6]; o1.w = d[7] * inv * gg[7] + bb[7];
    *reinterpret_cast<float4*>(&out[(row << 9) + c0]) = o0;
    *reinterpret_cast<float4*>(&out[(row << 9) + c0 + 4]) = o1;
  }
}

// ---------------------------------------------------------------------------
// SPLIT-KV MFMA flash attention: one block = 8 waves (512 threads) per
// (b, h, 128-q-rows, KV-half of 512 keys) -> 1024 blocks, XCD-swizzled
// (8 consecutive ids share (bh,half) KV panel). Single-buffered K/V (36.9KB
// LDS -> 4 blocks/CU = 32 waves/CU), 2 barriers per KV tile (R16 structure):
// barrier A after softmax (Ks reads done) -> prefetched K written during PV;
// barrier B after PV (VsT reads done) -> V written. Partial O (unnormalized
// f32) + per-row (m,l) stored; combine kernel merges halves exactly.
// ---------------------------------------------------------------------------
__global__ __launch_bounds__(512) void attn_mfma_kernel(
    const short* __restrict__ q, const short* __restrict__ k,
    const short* __restrict__ vt, float* __restrict__ pO, float2* __restrict__ ml) {
  __shared__ __align__(16) short Ks[64][72];
  __shared__ __align__(16) short VsT[64][72];
  __shared__ __align__(16) short Ps[2][64][72];  // also Q staging (128*72)
  const int bx = ((blockIdx.x & 7) << 7) | (blockIdx.x >> 3);  // nwg=1024, cpx=128
  const int qt = bx & 7, half = (bx >> 3) & 1, bh = bx >> 4;
  const int tid = threadIdx.x, lane = tid & 63, w = tid >> 6;
  const int a = w >> 2, wl = w & 3;
  const int t0 = qt << 7;  // 128 q-rows per block
  const short* qbase = q + ((size_t)bh << 16) + ((size_t)t0 << 6);
  const short* kbase = k + ((size_t)bh << 16) + ((size_t)(half * 512) << 6);
  const short* vtbase = vt + ((size_t)bh << 16) + half * 512;  // v^T col offset
  const int sr = tid >> 3, sc = (tid & 7) << 3;  // staging: row 0..63, col chunk
  short* Qtmp = &Ps[0][0][0];
  // ---- stage Q (128 rows into Ps area) + K/V tile 0
  {
#pragma unroll
    for (int j = 0; j < 2; ++j) {
      const int idx = j * 512 + tid;
      const int qr_ = idx >> 3, qc = (idx & 7) << 3;
      const s8v v = *reinterpret_cast<const s8v*>(&qbase[(size_t)qr_ * 64 + qc]);
      *reinterpret_cast<s8v*>(&Qtmp[qr_ * 72 + qc]) = v;
    }
    const s8v k0v = *reinterpret_cast<const s8v*>(&kbase[(size_t)sr * 64 + sc]);
    *reinterpret_cast<s8v*>(&Ks[sr][sc]) = k0v;
    const s8v v0v = *reinterpret_cast<const s8v*>(&vtbase[((size_t)sr << 10) + sc]);
    *reinterpret_cast<s8v*>(&VsT[sr][sc]) = v0v;
  }
  __syncthreads();
  const int fr = lane & 15, fg = lane >> 4;
  const int koff0 = fg << 3;
  bf16x8 qf[2];
  qf[0] = *reinterpret_cast<const bf16x8*>(&Qtmp[(a * 64 + wl * 16 + fr) * 72 + koff0]);
  qf[1] = *reinterpret_cast<const bf16x8*>(&Qtmp[(a * 64 + wl * 16 + fr) * 72 + 32 + koff0]);
  __syncthreads();  // all Q reads done before Ps overwrite
  float m[4], l[4];
  f32x4 outv[4];
#pragma unroll
  for (int r = 0; r < 4; ++r) { m[r] = -1e30f; l[r] = 0.f; }
#pragma unroll
  for (int n = 0; n < 4; ++n) outv[n] = (f32x4){0.f, 0.f, 0.f, 0.f};

  for (int i = 0; i < 8; ++i) {  // 8 KV tiles = 512 keys (this half)
    s8v nk, nv;
    const bool pf = (i < 7);
    if (pf) {
      const int kn = (i + 1) << 6;
      nk = *reinterpret_cast<const s8v*>(&kbase[(size_t)(kn + sr) * 64 + sc]);
      nv = *reinterpret_cast<const s8v*>(&vtbase[((size_t)sr << 10) + kn + sc]);
    }
    f32x4 sacc[4];
    __builtin_amdgcn_s_setprio(1);
#pragma unroll
    for (int n = 0; n < 4; ++n) {
      const bf16x8 kf0 = *reinterpret_cast<const bf16x8*>(&Ks[n * 16 + fr][koff0]);
      const bf16x8 kf1 = *reinterpret_cast<const bf16x8*>(&Ks[n * 16 + fr][32 + koff0]);
      sacc[n] = (f32x4){0.f, 0.f, 0.f, 0.f};
      sacc[n] = __builtin_amdgcn_mfma_f32_16x16x32_bf16(qf[0], kf0, sacc[n], 0, 0, 0);
      sacc[n] = __builtin_amdgcn_mfma_f32_16x16x32_bf16(qf[1], kf1, sacc[n], 0, 0, 0);
    }
    __builtin_amdgcn_s_setprio(0);
    float vm[4];
    bool ok = true;
#pragma unroll
    for (int r = 0; r < 4; ++r) {
      vm[r] = fmaxf(fmaxf(sacc[0][r], sacc[1][r]), fmaxf(sacc[2][r], sacc[3][r]));
      ok = ok && (vm[r] <= m[r] + 8.f);
    }
    if (__all(ok)) {
#pragma unroll
      for (int r = 0; r < 4; ++r) {
        const float p0 = __expf(sacc[0][r] - m[r]), p1 = __expf(sacc[1][r] - m[r]);
        const float p2 = __expf(sacc[2][r] - m[r]), p3 = __expf(sacc[3][r] - m[r]);
        l[r] += p0 + p1 + p2 + p3;
        const int qr = wl * 16 + (fg << 2) + r;
        Ps[a][qr][fr] = f2bf(p0);
        Ps[a][qr][16 + fr] = f2bf(p1);
        Ps[a][qr][32 + fr] = f2bf(p2);
        Ps[a][qr][48 + fr] = f2bf(p3);
      }
    } else {
#pragma unroll
      for (int r = 0; r < 4; ++r) {
        float rm = vm[r];
        rm = fmaxf(rm, __shfl_xor(rm, 1));
        rm = fmaxf(rm, __shfl_xor(rm, 2));
        rm = fmaxf(rm, __shfl_xor(rm, 4));
        rm = fmaxf(rm, __shfl_xor(rm, 8));
        const float nm = fmaxf(m[r], rm);
        const float al = __expf(m[r] - nm);
        m[r] = nm;
        const float p0 = __expf(sacc[0][r] - nm), p1 = __expf(sacc[1][r] - nm);
        const float p2 = __expf(sacc[2][r] - nm), p3 = __expf(sacc[3][r] - nm);
        l[r] = l[r] * al + (p0 + p1 + p2 + p3);
        outv[0][r] *= al; outv[1][r] *= al; outv[2][r] *= al; outv[3][r] *= al;
        const int qr = wl * 16 + (fg << 2) + r;
        Ps[a][qr][fr] = f2bf(p0);
        Ps[a][qr][16 + fr] = f2bf(p1);
        Ps[a][qr][32 + fr] = f2bf(p2);
        Ps[a][qr][48 + fr] = f2bf(p3);
      }
    }
    __syncthreads();  // barrier A: all Ks reads done (Ps is wave-private)
    if (pf) {         // next-K LDS write overlaps PV (PV reads only VsT/Ps)
      *reinterpret_cast<s8v*>(&Ks[sr][sc]) = nk;
    }
    __builtin_amdgcn_s_setprio(1);
    const bf16x8 pa0 = *reinterpret_cast<const bf16x8*>(&Ps[a][wl * 16 + fr][koff0]);
    const bf16x8 pa1 = *reinterpret_cast<const bf16x8*>(&Ps[a][wl * 16 + fr][32 + koff0]);
#pragma unroll
    for (int n = 0; n < 4; ++n) {
      const bf16x8 vf0 = *reinterpret_cast<const bf16x8*>(&VsT[n * 16 + fr][koff0]);
      const bf16x8 vf1 = *reinterpret_cast<const bf16x8*>(&VsT[n * 16 + fr][32 + koff0]);
      outv[n] = __builtin_amdgcn_mfma_f32_16x16x32_bf16(pa0, vf0, outv[n], 0, 0, 0);
      outv[n] = __builtin_amdgcn_mfma_f32_16x16x32_bf16(pa1, vf1, outv[n], 0, 0, 0);
    }
    __builtin_amdgcn_s_setprio(0);
    __syncthreads();  // barrier B: VsT reads done; Ks write visible for next QK
    if (pf) {         // V write; next PV is beyond barrier A of tile i+1
      *reinterpret_cast<s8v*>(&VsT[sr][sc]) = nv;
    }
  }
  // ---- write partial O (unnormalized f32) + per-row (m, l)
#pragma unroll
  for (int r = 0; r < 4; ++r) {
    float L = l[r];
    L += __shfl_xor(L, 1);
    L += __shfl_xor(L, 2);
    L += __shfl_xor(L, 4);
    L += __shfl_xor(L, 8);
    const int trow = t0 + a * 64 + wl * 16 + (fg << 2) + r;
    const size_t base = (size_t)half * 4194304 + ((size_t)bh << 16) + (size_t)trow * 64;
#pragma unroll
    for (int n = 0; n < 4; ++n)
      pO[base + n * 16 + fr] = outv[n][r];
    if (fr == 0)
      ml[half * 65536 + (bh << 10) + trow] = make_float2(m[r], L);
  }
}

// ---------------------------------------------------------------------------
// Split-KV combine: exact online-softmax merge of the two halves -> ctx bf16.
// 1M threads: each handles 4 dims of one (b,h,t) row.
// ---------------------------------------------------------------------------
__global__ __launch_bounds__(256) void attn_combine_kernel(
    const float* __restrict__ pO, const float2* __restrict__ ml,
    short* __restrict__ ctx) {
  const int g = blockIdx.x * 256 + threadIdx.x;  // 1M
  const int row = g >> 4, dq = (g & 15) << 2;
  const float2 ml0 = ml[row];
  const float2 ml1 = ml[65536 + row];
  const float M = fmaxf(ml0.x, ml1.x);
  const float a0 = __expf(ml0.x - M), a1 = __expf(ml1.x - M);
  const float inv = 1.f / (ml0.y * a0 + ml1.y * a1);
  const float4 o0 = *reinterpret_cast<const float4*>(&pO[(size_t)row * 64 + dq]);
  const float4 o1 = *reinterpret_cast<const float4*>(&pO[4194304 + (size_t)row * 64 + dq]);
  const int b = row >> 13, h = (row >> 10) & 7, t = row & 1023;
  s4v o;
  o[0] = f2bf((o0.x * a0 + o1.x * a1) * inv);
  o[1] = f2bf((o0.y * a0 + o1.y * a1) * inv);
  o[2] = f2bf((o0.z * a0 + o1.z * a1) * inv);
  o[3] = f2bf((o0.w * a0 + o1.w * a1) * inv);
  *reinterpret_cast<s4v*>(&ctx[(((size_t)((b << 10) | t)) << 9) + (h << 6) + dq]) = o;
}

// ---------------------------------------------------------------------------
// LDS-tiled depthwise conv K=31 SAME + fused BN partial stats (f32).
// ---------------------------------------------------------------------------
__global__ __launch_bounds__(256) void dwconv_kernel(
    const short* __restrict__ in, const float* __restrict__ w,
    const float* __restrict__ bias, short* __restrict__ out,
    float* __restrict__ ps, float* __restrict__ pq) {
  __shared__ __align__(16) short tile[286 * 72];
  __shared__ float wlds[31 * 64];
  const int id = blockIdx.x;  // 512
  const int ct = id & 15, tt = (id >> 4) & 3;
  const size_t b = id >> 6;
  const int c0 = ct << 6, t0 = tt << 8;
  const int tid = threadIdx.x;
  for (int i = tid; i < 31 * 64; i += 256) {
    const int kk = i >> 6, c = i & 63;
    wlds[i] = w[kk * 1024 + c0 + c];
  }
  for (int i = tid; i < 286 * 8; i += 256) {
    const int row = i >> 3, seg = i & 7;
    const int gt = t0 - 15 + row;
    s8v val = {};
    if (gt >= 0 && gt < 1024)
      val = *reinterpret_cast<const s8v*>(&in[(b << 20) + ((size_t)gt << 10) + c0 + (seg << 3)]);
    *reinterpret_cast<s8v*>(&tile[row * 72 + (seg << 3)]) = val;
  }
  __syncthreads();
  const int cg = tid & 7, tg = tid >> 3;
  const int tl = tg << 3;
  float acc[8][8];
  const float4 b0 = *reinterpret_cast<const float4*>(&bias[c0 + (cg << 3)]);
  const float4 b1 = *reinterpret_cast<const float4*>(&bias[c0 + (cg << 3) + 4]);
#pragma unroll
  for (int t = 0; t < 8; ++t) {
    acc[t][0] = b0.x; acc[t][1] = b0.y; acc[t][2] = b0.z; acc[t][3] = b0.w;
    acc[t][4] = b1.x; acc[t][5] = b1.y; acc[t][6] = b1.z; acc[t][7] = b1.w;
  }
  for (int kk = 0; kk < 31; ++kk) {
    const float4 w0 = *reinterpret_cast<const float4*>(&wlds[kk * 64 + (cg << 3)]);
    const float4 w1 = *reinterpret_cast<const float4*>(&wlds[kk * 64 + (cg << 3) + 4]);
#pragma unroll
    for (int t = 0; t < 8; ++t) {
      const s8v xv = *reinterpret_cast<const s8v*>(&tile[(tl + t + kk) * 72 + (cg << 3)]);
      acc[t][0] = fmaf(bf2f(xv[0]), w0.x, acc[t][0]);
      acc[t][1] = fmaf(bf2f(xv[1]), w0.y, acc[t][1]);
      acc[t][2] = fmaf(bf2f(xv[2]), w0.z, acc[t][2]);
      acc[t][3] = fmaf(bf2f(xv[3]), w0.w, acc[t][3]);
      acc[t][4] = fmaf(bf2f(xv[4]), w1.x, acc[t][4]);
      acc[t][5] = fmaf(bf2f(xv[5]), w1.y, acc[t][5]);
      acc[t][6] = fmaf(bf2f(xv[6]), w1.z, acc[t][6]);
      acc[t][7] = fmaf(bf2f(xv[7]), w1.w, acc[t][7]);
    }
  }
#pragma unroll
  for (int t = 0; t < 8; ++t) {
    s8v o;
#pragma unroll
    for (int j = 0; j < 8; ++j) o[j] = f2bf(acc[t][j]);
    *reinterpret_cast<s8v*>(&out[(b << 20) + ((size_t)(t0 + tl + t) << 10) + c0 + (cg << 3)]) = o;
  }
  // ---- fused BN partial stats
  float s8_[8], q8_[8];
#pragma unroll
  for (int j = 0; j < 8; ++j) {
    float S = 0.f, Q = 0.f;
#pragma unroll
    for (int t = 0; t < 8; ++t) {
      S += acc[t][j];
      Q = fmaf(acc[t][j], acc[t][j], Q);
    }
    s8_[j] = S;
    q8_[j] = Q;
  }
  __syncthreads();
  float* fred = (float*)tile;
#pragma unroll
  for (int j = 0; j < 8; ++j) {
    fred[tid * 16 + j] = s8_[j];
    fred[tid * 16 + 8 + j] = q8_[j];
  }
  __syncthreads();
  if (tid < 64) {
    const int cg_ = tid >> 3, j_ = tid & 7;
    float S = 0.f, Q = 0.f;
    for (int tg_ = 0; tg_ < 32; ++tg_) {
      const int th = tg_ * 8 + cg_;
      S += fred[th * 16 + j_];
      Q += fred[th * 16 + 8 + j_];
    }
    const int pidx = ((int)b << 2) + tt;  // 0..31
    ps[pidx * 1024 + c0 + tid] = S;
    pq[pidx * 1024 + c0 + tid] = Q;
  }
}

// ---------------------------------------------------------------------------
// BN finalize (reduce 32 partials) + apply+swish.
// ---------------------------------------------------------------------------
__global__ __launch_bounds__(256) void bn_finalize_kernel(
    const float* __restrict__ ps, const float* __restrict__ pq, float* __restrict__ stats) {
  const int c = blockIdx.x * 256 + threadIdx.x;
  float s = 0.f, q = 0.f;
  for (int i = 0; i < 32; ++i) {
    s += ps[i * 1024 + c];
    q += pq[i * 1024 + c];
  }
  const float mean = s * (1.f / 8192.f);
  const float var = q * (1.f / 8192.f) - mean * mean;
  stats[c] = mean;
  stats[1024 + c] = rsqrtf(fmaxf(var, 0.f) + 1e-5f);
}

__global__ __launch_bounds__(256) void bn_apply_kernel(
    const short* __restrict__ y, const float* __restrict__ g, const float* __restrict__ b,
    const float* __restrict__ stats, short* __restrict__ out) {
  const size_t i = (size_t)blockIdx.x * 256 + threadIdx.x;
  const size_t f = i << 2;
  const int c = (int)(f & 1023);
  const s4v yv = *reinterpret_cast<const s4v*>(&y[f]);
  s4v o;
#pragma unroll
  for (int j = 0; j < 4; ++j) {
    const float v = (bf2f(yv[j]) - stats[c + j]) * stats[1024 + c + j] * g[c + j] + b[c + j];
    o[j] = f2bf(v * sigmoid_(v));
  }
  *reinterpret_cast<s4v*>(&out[f]) = o;
}

// ---------------------------------------------------------------------------
extern "C" void kernel_launch(void* const* d_in, const int* in_sizes, int n_in,
                              void* d_out, int out_size, void* d_ws, size_t ws_size,
                              hipStream_t stream) {
  const float* x        = (const float*)d_in[0];
  const float* ffn1_w1  = (const float*)d_in[1];
  const float* ffn1_b1  = (const float*)d_in[2];
  const float* ffn1_w2  = (const float*)d_in[3];
  const float* ffn1_b2  = (const float*)d_in[4];
  const float* ln_att_g = (const float*)d_in[5];
  const float* ln_att_b = (const float*)d_in[6];
  const float* wq       = (const float*)d_in[7];
  const float* bq       = (const float*)d_in[8];
  const float* wk       = (const float*)d_in[9];
  const float* bk       = (const float*)d_in[10];
  const float* wv       = (const float*)d_in[11];
  const float* bv       = (const float*)d_in[12];
  const float* wo_      = (const float*)d_in[13];
  const float* bo       = (const float*)d_in[14];
  const float* cln_g    = (const float*)d_in[15];
  const float* cln_b    = (const float*)d_in[16];
  const float* pw1_w    = (const float*)d_in[17];
  const float* pw1_b    = (const float*)d_in[18];
  const float* dw_w     = (const float*)d_in[19];
  const float* dw_b     = (const float*)d_in[20];
  const float* bn_g     = (const float*)d_in[21];
  const float* bn_b     = (const float*)d_in[22];
  const float* pw2_w    = (const float*)d_in[23];
  const float* pw2_b    = (const float*)d_in[24];
  const float* ffn2_w1  = (const float*)d_in[25];
  const float* ffn2_b1  = (const float*)d_in[26];
  const float* ffn2_w2  = (const float*)d_in[27];
  const float* ffn2_b2  = (const float*)d_in[28];
  const float* ln_out_g = (const float*)d_in[29];
  const float* ln_out_b = (const float*)d_in[30];

  char* wsb = (char*)d_ws;
  const size_t MB = 1u << 20;
  short* buf_y = (short*)(wsb);            // residual stream bf16 (8 MB)
  char* Bre = wsb + 16 * MB;
  short* qkv16 = (short*)(Bre);            // q,k (B,H,T,64) + v^T (B,H,64,T), 24 MB
  short* lnq  = (short*)(Bre + 48 * MB);
  short* ctx  = (short*)(Bre + 56 * MB);
  short* h1   = (short*)(Bre);
  short* xb   = (short*)(Bre + 16 * MB);
  short* gluo = (short*)(Bre);
  short* bno  = (short*)(Bre + 48 * MB);
  char* Cre = wsb + 80 * MB;
  short* lnc  = (short*)(Cre);             // conv LN out bf16 (8 MB)
  short* dwo16= (short*)(Cre + 8 * MB);    // dwconv out bf16 (16 MB)
  float* pO   = (float*)(Cre);             // attn partial O f32 (32 MB, MHSA phase)
  char* Dre = wsb + 112 * MB;
  short* w_f1w1 = (short*)(Dre);
  short* w_f1w2 = (short*)(Dre + 1 * MB);
  short* w_qkv  = (short*)(Dre + 2 * MB);
  short* w_wo   = (short*)(Dre + 3 * MB + 512 * 1024);
  short* w_pw1  = (short*)(Dre + 4 * MB);
  short* w_pw2  = (short*)(Dre + 6 * MB);
  short* w_f2w1 = (short*)(Dre + 7 * MB);
  short* w_f2w2 = (short*)(Dre + 8 * MB);
  float* bqkv   = (float*)(Dre + 9 * MB);
  float* ps     = (float*)(Dre + 9 * MB + 8192);
  float* pq     = (float*)(Dre + 10 * MB + 8192);
  float* stats  = (float*)(Dre + 11 * MB + 8192);
  float* rtbl   = (float*)(Dre + 12 * MB);
  float2* ml    = (float2*)(Dre + 13 * MB);  // [2][65536] (m,l) = 1 MB

  const dim3 blk(256);

  // ---- single mega-prep
  prep_kernel<<<6022, blk, 0, stream>>>(
      x, xb, ffn1_w1, w_f1w1, ffn1_w2, w_f1w2, wq, wk, wv, w_qkv, wo_, w_wo,
      pw1_w, w_pw1, pw2_w, w_pw2, ffn2_w1, w_f2w1, ffn2_w2, w_f2w2,
      bq, bk, bv, bqkv, rtbl);

  // ---- FFN1: y = x + 0.5*(swish(x@w1+b1)@w2+b2)
  mgemm<64, 128, 64, 1, 512><<<dim3(8, 128), dim3(512), 0, stream>>>(xb, w_f1w1, ffn1_b1, nullptr, nullptr, h1, M_ROWS, 1024, 512);
  mgemm<64, 128, 64, 3, 512><<<dim3(4, 128), dim3(512), 0, stream>>>(h1, w_f1w2, ffn1_b2, nullptr, xb, buf_y, M_ROWS, 512, 1024);

  // ---- MHSA (split-KV attention + exact combine)
  ln_kernel<short><<<2048, blk, 0, stream>>>(buf_y, ln_att_g, ln_att_b, lnq);
  mgemm<128, 128, 32, 4, 512><<<dim3(12, 64), dim3(512), 0, stream>>>(lnq, w_qkv, bqkv, rtbl, nullptr, qkv16, M_ROWS, 1536, 512);
  attn_mfma_kernel<<<1024, dim3(512), 0, stream>>>(qkv16, qkv16 + 4194304, qkv16 + 8388608, pO, ml);
  attn_combine_kernel<<<4096, blk, 0, stream>>>(pO, ml, ctx);
  mgemm<64, 128, 64, 2, 512><<<dim3(4, 128), dim3(512), 0, stream>>>(ctx, w_wo, bo, nullptr, buf_y, buf_y, M_ROWS, 512, 512);

  // ---- Conv module (pw1 128x256; dwconv emits BN partial stats)
  ln_kernel<short><<<2048, blk, 0, stream>>>(buf_y, cln_g, cln_b, lnc);
  mgemm<128, 256, 32, 6, 512><<<dim3(8, 64), dim3(512), 0, stream>>>(lnc, w_pw1, pw1_b, nullptr, nullptr, gluo, M_ROWS, 2048, 512);
  dwconv_kernel<<<512, blk, 0, stream>>>(gluo, dw_w, dw_b, dwo16, ps, pq);
  bn_finalize_kernel<<<4, blk, 0, stream>>>(ps, pq, stats);
  bn_apply_kernel<<<8192, blk, 0, stream>>>(dwo16, bn_g, bn_b, stats, bno);
  mgemm<64, 128, 64, 2, 512><<<dim3(4, 128), dim3(512), 0, stream>>>(bno, w_pw2, pw2_b, nullptr, buf_y, buf_y, M_ROWS, 512, 1024);

  // ---- FFN2
  mgemm<64, 128, 64, 1, 512><<<dim3(8, 128), dim3(512), 0, stream>>>(buf_y, w_f2w1, ffn2_b1, nullptr, nullptr, h1, M_ROWS, 1024, 512);
  mgemm<64, 128, 64, 3, 512><<<dim3(4, 128), dim3(512), 0, stream>>>(h1, w_f2w2, ffn2_b2, nullptr, buf_y, buf_y, M_ROWS, 512, 1024);

  // ---- Final LN -> d_out (f32)
  ln_kernel<float><<<2048, blk, 0, stream>>>(buf_y, ln_out_g, ln_out_b, (float*)d_out);
}

// Round 23
// 247.697 us; speedup vs baseline: 1.0317x; 1.0317x over previous
//
#include <hip/hip_runtime.h>
#include <hip/hip_bf16.h>

// ---------------------------------------------------------------------------
// Conformer block: bf16-MFMA GEMMs (XCD-swizzled, counted-vmcnt; small GEMMs
// 64x128x64 XOR-swizzled 8-wave; QKV/pw1 128x128x32 8-wave, vstg aliased on
// smem) + bf16-MFMA flash attention (128 q-rows, 8 waves, dbuf K/V,
// 1 barrier/tile) + LDS-tiled depthwise conv with fused BN stats +
// wave-per-row LN + mega-prep.
// B=8, T=1024, D=512, HID=1024, C=1024, K=31, H=8, dh=64.  M = B*T = 8192.
// ---------------------------------------------------------------------------

#define M_ROWS 8192

using bf16x8 = __attribute__((ext_vector_type(8))) short;
using f32x4  = __attribute__((ext_vector_type(4))) float;
using s8v    = __attribute__((ext_vector_type(8))) short;
using s4v    = __attribute__((ext_vector_type(4))) short;

__device__ __forceinline__ float sigmoid_(float v) { return 1.f / (1.f + expf(-v)); }

__device__ __forceinline__ float bf2f(short s) {
  return __uint_as_float(((unsigned)(unsigned short)s) << 16);
}
__device__ __forceinline__ short f2bf(float f) {
  __hip_bfloat16 h = __float2bfloat16(f);
  return *reinterpret_cast<short*>(&h);
}

__device__ __forceinline__ void gl16(const void* g, void* l) {
  __builtin_amdgcn_global_load_lds((const __attribute__((address_space(1))) void*)g,
                                   (__attribute__((address_space(3))) void*)l, 16, 0, 0);
}

// ---------------------------------------------------------------------------
// bf16 MFMA GEMM: outb[M,N] = epi(A[M,K] @ Bt[N,K]^T + bias).
// BK=32: linear LDS. BK=64: XOR-swizzled (linear LDS dest + inverse-swizzled
// GLOBAL source + same XOR on frag read). Counted-vmcnt 2-buffer K-loop.
// Single smem[] holds As|Bs; EPI4's v^T staging buffer ALIASES smem (only
// used after the K-loop, behind a barrier).
// EPI: 1 swish->bf16 | 2 resb+acc+bias->bf16 | 3 resb+0.5*(acc+bias)->bf16
//      4 QKV: table-RoPE q/k ->bf16 (B,H,T,64); v->bf16 (B,H,64,T)
//      6 pw1+GLU (packed weights): a*sigmoid(gate)->bf16
// ---------------------------------------------------------------------------
template <int BM, int BN, int BK, int EPI, int THREADS>
__global__ __launch_bounds__(THREADS) void mgemm(
    const short* __restrict__ A, const short* __restrict__ Bt,
    const float* __restrict__ bias, const float* __restrict__ res,
    const short* __restrict__ resb, short* __restrict__ outb, int M, int N, int K) {
  constexpr int NW = THREADS / 64;         // waves per block
  constexpr int WR = BM / 64;              // wave-grid rows
  constexpr int WC = NW / WR;              // wave-grid cols
  constexpr int NF = BN / (16 * WC);       // N-frags per wave
  constexpr int CPW = BN / WC;             // cols per wave
  constexpr int KH = BK / 32;
  constexpr int RPP = THREADS / (BK / 8);  // rows staged per pass
  constexpr int APASS = BM / RPP;
  constexpr int BPASS = BN / RPP;
  constexpr int LPS = APASS + BPASS;       // loads per stage per thread
  __shared__ __align__(16) short smem[2 * BM * BK + 2 * BN * BK];
  short* As0 = smem;
  short* Bs0 = smem + 2 * BM * BK;
  const int tid = threadIdx.x;
  const int lane = tid & 63, wid = tid >> 6;
  const int wr = wid / WC, wc = wid % WC;
  const int nbx = gridDim.x;
  const int nwg = nbx * gridDim.y;
  int id = blockIdx.y * nbx + blockIdx.x;
  id = (id & 7) * (nwg >> 3) + (id >> 3);
  const int bm = (id / nbx) * BM;
  const int bn = (id % nbx) * BN;
  f32x4 acc[4][NF];
#pragma unroll
  for (int m = 0; m < 4; ++m)
#pragma unroll
    for (int n = 0; n < NF; ++n) acc[m][n] = (f32x4){0.f, 0.f, 0.f, 0.f};
  const short* Ablk = A + (size_t)bm * K;
  const short* Bblk = Bt + (size_t)bn * K;
  const int jl = tid & (BK / 8 - 1);
  const int r0 = tid / (BK / 8);
  const int ks = ((BK == 64) ? (jl ^ (r0 & 7)) : jl) << 3;
#define STAGE(buf, k0)                                                                 \
  do {                                                                                 \
    _Pragma("unroll")                                                                  \
    for (int p = 0; p < APASS; ++p)                                                    \
      gl16(Ablk + (size_t)(r0 + p * RPP) * K + (k0) + ks,                              \
           (char*)(As0 + (buf) * BM * BK) + p * (THREADS * 16) + wid * 1024);          \
    _Pragma("unroll")                                                                  \
    for (int p = 0; p < BPASS; ++p)                                                    \
      gl16(Bblk + (size_t)(r0 + p * RPP) * K + (k0) + ks,                              \
           (char*)(Bs0 + (buf) * BN * BK) + p * (THREADS * 16) + wid * 1024);          \
  } while (0)

  STAGE(0, 0);
  STAGE(1, BK);
  const int NS = K / BK;
  const int fr = lane & 15, fg = lane >> 4;
  const int arow = wr * 64 + fr;
  const int brow = wc * CPW + fr;
  for (int i = 0; i < NS; ++i) {
    if (i + 1 < NS) {
      if constexpr (LPS == 6)      asm volatile("s_waitcnt vmcnt(6)" ::: "memory");
      else if constexpr (LPS == 4) asm volatile("s_waitcnt vmcnt(4)" ::: "memory");
      else if constexpr (LPS == 3) asm volatile("s_waitcnt vmcnt(3)" ::: "memory");
      else                         asm volatile("s_waitcnt vmcnt(2)" ::: "memory");
    } else {
      asm volatile("s_waitcnt vmcnt(0)" ::: "memory");
    }
    __builtin_amdgcn_s_barrier();
    asm volatile("" ::: "memory");
    const int cur = i & 1;
    bf16x8 af[KH][4], bfr[KH][NF];
#pragma unroll
    for (int kk = 0; kk < KH; ++kk) {
      const int cx = (BK == 64) ? (((((kk << 2) + fg)) ^ (fr & 7)) << 3)
                                : ((fg << 3) + kk * 32);
#pragma unroll
      for (int m = 0; m < 4; ++m)
        af[kk][m] = *reinterpret_cast<const bf16x8*>(
            &As0[cur * BM * BK + (arow + m * 16) * BK + cx]);
#pragma unroll
      for (int n = 0; n < NF; ++n)
        bfr[kk][n] = *reinterpret_cast<const bf16x8*>(
            &Bs0[cur * BN * BK + (brow + n * 16) * BK + cx]);
    }
    asm volatile("s_waitcnt lgkmcnt(0)" ::: "memory");
    __builtin_amdgcn_s_barrier();
    if ((i + 2) * BK < K) STAGE(cur, (i + 2) * BK);
#pragma unroll
    for (int kk = 0; kk < KH; ++kk)
#pragma unroll
      for (int m = 0; m < 4; ++m)
#pragma unroll
        for (int n = 0; n < NF; ++n)
          acc[m][n] = __builtin_amdgcn_mfma_f32_16x16x32_bf16(af[kk][m], bfr[kk][n],
                                                              acc[m][n], 0, 0, 0);
  }
#undef STAGE
  const int orow0 = bm + wr * 64 + ((lane >> 4) << 2);
  const int ocol0 = bn + wc * CPW + fr;

  if constexpr (EPI == 4) {
    const int sel = bn >> 9;
    const float2* tbl = (const float2*)res;  // [1024][32] (cos,sin)
    if (sel == 2) {
      // v^T staging buffer aliases smem (safe: first use is behind a barrier).
      short* vstg = smem;  // needs 64*132 = 8448 shorts <= smem size
      const int b_ = bm >> 10, t0v = bm & 1023;
      const int hb = (bn & 511) >> 6;
#pragma unroll
      for (int pass = 0; pass < 2; ++pass) {
        __syncthreads();
        if (((wc * CPW) >> 6) == pass) {
          const int dlb = (wc * CPW) & 63;
#pragma unroll
          for (int m = 0; m < 4; ++m) {
            const int rl = wr * 64 + ((lane >> 4) << 2) + m * 16;
#pragma unroll
            for (int n = 0; n < NF; ++n) {
              const int dl = dlb + n * 16 + fr;
              const float bv = bias[bn + pass * 64 + dl];
#pragma unroll
              for (int r = 0; r < 4; ++r)
                vstg[dl * 132 + rl + r] = f2bf(acc[m][n][r] + bv);
            }
          }
        }
        __syncthreads();
        for (int c = tid; c < 1024; c += THREADS) {
          const int d = c >> 4, t8 = (c & 15) << 3;
          const s8v val = *reinterpret_cast<const s8v*>(&vstg[d * 132 + t8]);
          *reinterpret_cast<s8v*>(
              &outb[(size_t)8388608 + (((size_t)((b_ << 3) + hb + pass)) << 16) +
                    ((size_t)d << 10) + t0v + t8]) = val;
        }
      }
    } else {
      const float qsc = (sel == 0) ? 0.04419417382415922f : 1.f;  // 1/sqrt(512)
#pragma unroll
      for (int n = 0; n < NF; ++n) {
        const int col = ocol0 + n * 16;
        const int h = (col >> 6) & 7, d = col & 63;
        const int p = d >> 1;
        const float bv = bias[col];
#pragma unroll
        for (int m = 0; m < 4; ++m) {
#pragma unroll
          for (int r = 0; r < 4; ++r) {
            const int row = orow0 + m * 16 + r;
            const int b_ = row >> 10, t_ = row & 1023;
            const int pos = (sel == 0) ? h : t_;
            const float2 cs = tbl[pos * 32 + p];
            float vv = acc[m][n][r] + bv;
            const float pv = __shfl_xor(vv, 1);
            float o = ((lane & 1) == 0) ? (vv * cs.x - pv * cs.y) : (vv * cs.x + pv * cs.y);
            outb[(size_t)sel * 4194304 + (((size_t)((b_ << 3) + h)) << 16) + ((size_t)t_ << 6) + d] =
                f2bf(o * qsc);
          }
        }
      }
    }
  } else if constexpr (EPI == 6) {
    // Packed GLU epilogue, generic: per frag-pair (2np,2np+1) = (a,gate).
#pragma unroll
    for (int m = 0; m < 4; ++m) {
#pragma unroll
      for (int np = 0; np < NF / 2; ++np) {
        const int colbase = bn + wc * CPW + ((2 * np) << 4);
        const int j = colbase >> 7;
        const int u = (colbase >> 5) & 3;
        const int gc = (j << 6) + (u << 4) + fr;
        const float ba = bias[gc];
        const float bg = bias[1024 + gc];
#pragma unroll
        for (int r = 0; r < 4; ++r) {
          const int row = orow0 + m * 16 + r;
          const float a = acc[m][2 * np][r] + ba;
          const float g = acc[m][2 * np + 1][r] + bg;
          outb[(size_t)row * 1024 + gc] = f2bf(a * sigmoid_(g));
        }
      }
    }
  } else {
#pragma unroll
    for (int m = 0; m < 4; ++m) {
#pragma unroll
      for (int n = 0; n < NF; ++n) {
        const int col = ocol0 + n * 16;
        const float bv = bias[col];
#pragma unroll
        for (int r = 0; r < 4; ++r) {
          const int row = orow0 + m * 16 + r;
          float v = acc[m][n][r] + bv;
          if constexpr (EPI == 1) {
            v = v * sigmoid_(v);
          } else if constexpr (EPI == 2) {
            v += bf2f(resb[(size_t)row * N + col]);
          } else if constexpr (EPI == 3) {
            v = bf2f(resb[(size_t)row * N + col]) + 0.5f * v;
          }
          outb[(size_t)row * N + col] = f2bf(v);
        }
      }
    }
  }
}

// ---------------------------------------------------------------------------
// MEGA-PREP: all weight casts/transposes/packs + bias concat + rope table.
// ---------------------------------------------------------------------------
__device__ __forceinline__ void dev_cast8(const float* in, short* out, int i) {
  const float4 a = *reinterpret_cast<const float4*>(&in[(size_t)i * 8]);
  const float4 b = *reinterpret_cast<const float4*>(&in[(size_t)i * 8 + 4]);
  s8v o = { f2bf(a.x), f2bf(a.y), f2bf(a.z), f2bf(a.w),
            f2bf(b.x), f2bf(b.y), f2bf(b.z), f2bf(b.w) };
  *reinterpret_cast<s8v*>(&out[(size_t)i * 8]) = o;
}

__global__ __launch_bounds__(256) void prep_kernel(
    const float* __restrict__ x, short* __restrict__ xb,
    const float* __restrict__ f1w1, short* __restrict__ wf1w1,
    const float* __restrict__ f1w2, short* __restrict__ wf1w2,
    const float* __restrict__ wq, const float* __restrict__ wk,
    const float* __restrict__ wv, short* __restrict__ wqkv,
    const float* __restrict__ wo, short* __restrict__ wwo,
    const float* __restrict__ pw1, short* __restrict__ wpw1,
    const float* __restrict__ pw2, short* __restrict__ wpw2,
    const float* __restrict__ f2w1, short* __restrict__ wf2w1,
    const float* __restrict__ f2w2, short* __restrict__ wf2w2,
    const float* __restrict__ bq, const float* __restrict__ bk,
    const float* __restrict__ bv, float* __restrict__ bqkv,
    float* __restrict__ rtbl) {
  __shared__ float t[32][33];
  const int blk = blockIdx.x, tid = threadIdx.x;
  const float* tin = nullptr;
  short* tout = nullptr;
  int tK = 0, tN = 0, tr = 0, tnbx = 0;
  if (blk < 2048) {
    dev_cast8(x, xb, blk * 256 + tid);
    return;
  } else if (blk < 2560) { tin = f1w1; tout = wf1w1; tK = 512; tN = 1024; tr = blk - 2048; tnbx = 32; }
  else if (blk < 3072)   { tin = f1w2; tout = wf1w2; tK = 1024; tN = 512; tr = blk - 2560; tnbx = 16; }
  else if (blk < 3328)   { tin = wq; tout = wqkv; tK = 512; tN = 512; tr = blk - 3072; tnbx = 16; }
  else if (blk < 3584)   { tin = wk; tout = wqkv + 512 * 512; tK = 512; tN = 512; tr = blk - 3328; tnbx = 16; }
  else if (blk < 3840)   { tin = wv; tout = wqkv + 1024 * 512; tK = 512; tN = 512; tr = blk - 3584; tnbx = 16; }
  else if (blk < 4096)   { tin = wo; tout = wwo; tK = 512; tN = 512; tr = blk - 3840; tnbx = 16; }
  else if (blk < 4608) {
    const int idx = (blk - 4096) * 256 + tid;
    const int pc = idx >> 6, kk = (idx & 63) << 3;
    const int j = pc >> 7, s = (pc >> 4) & 7, fr = pc & 15;
    const int oc = ((s & 1) << 10) + (j << 6) + ((s >> 1) << 4) + fr;
    const float4 a = *reinterpret_cast<const float4*>(&pw1[(size_t)oc * 512 + kk]);
    const float4 b = *reinterpret_cast<const float4*>(&pw1[(size_t)oc * 512 + kk + 4]);
    s8v o = { f2bf(a.x), f2bf(a.y), f2bf(a.z), f2bf(a.w),
              f2bf(b.x), f2bf(b.y), f2bf(b.z), f2bf(b.w) };
    *reinterpret_cast<s8v*>(&wpw1[(size_t)pc * 512 + kk]) = o;
    return;
  } else if (blk < 4864) {
    dev_cast8(pw2, wpw2, (blk - 4608) * 256 + tid);
    return;
  } else if (blk < 5376) { tin = f2w1; tout = wf2w1; tK = 512; tN = 1024; tr = blk - 4864; tnbx = 32; }
  else if (blk < 5888)   { tin = f2w2; tout = wf2w2; tK = 1024; tN = 512; tr = blk - 5376; tnbx = 16; }
  else if (blk < 6016) {
    const int i = (blk - 5888) * 256 + tid;  // 32768
    const int tt = i >> 5, p = i & 31;
    const float inv = exp2f(-(float)p * 0.41524101186092f);
    float s, c;
    sincosf((float)tt * inv, &s, &c);
    rtbl[i * 2] = c;
    rtbl[i * 2 + 1] = s;
    return;
  } else {
    const int i = (blk - 6016) * 256 + tid;
    if (i < 1536) bqkv[i] = i < 512 ? bq[i] : (i < 1024 ? bk[i - 512] : bv[i - 1024]);
    return;
  }
  const int n0 = (tr % tnbx) << 5, k0 = (tr / tnbx) << 5;
  const int tx = tid & 31, ty = tid >> 5;
  for (int r = ty; r < 32; r += 8) t[r][tx] = tin[(size_t)(k0 + r) * tN + n0 + tx];
  __syncthreads();
  for (int r = ty; r < 32; r += 8) tout[(size_t)(n0 + r) * tK + k0 + tx] = f2bf(t[tx][r]);
}

// ---------------------------------------------------------------------------
// LayerNorm over last dim (512), bf16 input. One WAVE per row (4 rows/block).
// ---------------------------------------------------------------------------
template <typename OT>
__global__ __launch_bounds__(256) void ln_kernel(
    const short* __restrict__ in, const float* __restrict__ g,
    const float* __restrict__ b, OT* __restrict__ out) {
  const int tid = threadIdx.x, lane = tid & 63;
  const size_t row = ((size_t)blockIdx.x << 2) + (tid >> 6);
  const int c0 = lane << 3;
  const s8v v = *reinterpret_cast<const s8v*>(&in[(row << 9) + c0]);
  float f[8];
  float s = 0.f;
#pragma unroll
  for (int j = 0; j < 8; ++j) { f[j] = bf2f(v[j]); s += f[j]; }
  for (int o = 32; o; o >>= 1) s += __shfl_xor(s, o);
  const float mean = s * (1.f / 512.f);
  float d[8];
  float q = 0.f;
#pragma unroll
  for (int j = 0; j < 8; ++j) { d[j] = f[j] - mean; q = fmaf(d[j], d[j], q); }
  for (int o = 32; o; o >>= 1) q += __shfl_xor(q, o);
  const float inv = rsqrtf(q * (1.f / 512.f) + 1e-5f);
  const float4 g0 = *reinterpret_cast<const float4*>(&g[c0]);
  const float4 g1 = *reinterpret_cast<const float4*>(&g[c0 + 4]);
  const float4 b0 = *reinterpret_cast<const float4*>(&b[c0]);
  const float4 b1 = *reinterpret_cast<const float4*>(&b[c0 + 4]);
  const float gg[8] = {g0.x, g0.y, g0.z, g0.w, g1.x, g1.y, g1.z, g1.w};
  const float bb[8] = {b0.x, b0.y, b0.z, b0.w, b1.x, b1.y, b1.z, b1.w};
  if constexpr (sizeof(OT) == 2) {
    s8v o;
#pragma unroll
    for (int j = 0; j < 8; ++j) o[j] = f2bf(d[j] * inv * gg[j] + bb[j]);
    *reinterpret_cast<s8v*>(&out[(row << 9) + c0]) = o;
  } else {
    float4 o0, o1;
    o0.x = d[0] * inv * gg[0] + bb[0]; o0.y = d[1] * inv * gg[1] + bb[1];
    o0.z = d[2] * inv * gg[2] + bb[2]; o0.w = d[3] * inv * gg[3] + bb[3];
    o1.x = d[4] * inv * gg[4] + bb[4]; o1.y = d[5] * inv * gg[5] + bb[5];
    o1.z = d[6] * inv * gg[6] + bb[6]; o1.w = d[7] * inv * gg[7] + bb[7];
    *reinterpret_cast<float4*>(&out[(row << 9) + c0]) = o0;
    *reinterpret_cast<float4*>(&out[(row << 9) + c0 + 4]) = o1;
  }
}

// ---------------------------------------------------------------------------
// MFMA flash attention: one block = 8 WAVES (512 threads) per (b,h,128-q-rows)
// -> 512 blocks, XCD-swizzled. Waves 0-3 own q-tile A, waves 4-7 q-tile B.
// Double-buffered K/V LDS -> 1 barrier per KV tile (Ps is wave-private).
// Async K/V reg-prefetch; defer-max (THR=8); setprio around MFMA clusters.
// ---------------------------------------------------------------------------
__global__ __launch_bounds__(512) void attn_mfma_kernel(
    const short* __restrict__ q, const short* __restrict__ k,
    const short* __restrict__ vt, short* __restrict__ ctx) {
  __shared__ __align__(16) short Ks[2][64][72];
  __shared__ __align__(16) short VsT[2][64][72];
  __shared__ __align__(16) short Ps[2][64][72];  // also Q staging (128*72)
  const int bx = ((blockIdx.x & 7) << 6) | (blockIdx.x >> 3);  // nwg=512, cpx=64
  const int bh = bx >> 3, qt = bx & 7;
  const int b_ = bh >> 3, h_ = bh & 7;
  const int tid = threadIdx.x, lane = tid & 63, w = tid >> 6;
  const int a = w >> 2, wl = w & 3;
  const int t0 = qt << 7;  // 128 q-rows per block
  const short* qbase = q + ((size_t)bh << 16) + ((size_t)t0 << 6);
  const short* kbase = k + ((size_t)bh << 16);
  const short* vtbase = vt + ((size_t)bh << 16);
  const int sr = tid >> 3, sc = (tid & 7) << 3;  // staging: row 0..63, col chunk
  short* Qtmp = &Ps[0][0][0];
  // ---- stage Q (128 rows into Ps area) + K/V tile 0
  {
#pragma unroll
    for (int j = 0; j < 2; ++j) {
      const int idx = j * 512 + tid;
      const int qr_ = idx >> 3, qc = (idx & 7) << 3;
      const s8v v = *reinterpret_cast<const s8v*>(&qbase[(size_t)qr_ * 64 + qc]);
      *reinterpret_cast<s8v*>(&Qtmp[qr_ * 72 + qc]) = v;
    }
    const s8v k0v = *reinterpret_cast<const s8v*>(&kbase[(size_t)sr * 64 + sc]);
    *reinterpret_cast<s8v*>(&Ks[0][sr][sc]) = k0v;
    const s8v v0v = *reinterpret_cast<const s8v*>(&vtbase[((size_t)sr << 10) + sc]);
    *reinterpret_cast<s8v*>(&VsT[0][sr][sc]) = v0v;
  }
  __syncthreads();
  const int fr = lane & 15, fg = lane >> 4;
  const int koff0 = fg << 3;
  bf16x8 qf[2];
  qf[0] = *reinterpret_cast<const bf16x8*>(&Qtmp[(a * 64 + wl * 16 + fr) * 72 + koff0]);
  qf[1] = *reinterpret_cast<const bf16x8*>(&Qtmp[(a * 64 + wl * 16 + fr) * 72 + 32 + koff0]);
  __syncthreads();  // all Q reads done before Ps overwrite
  float m[4], l[4];
  f32x4 outv[4];
#pragma unroll
  for (int r = 0; r < 4; ++r) { m[r] = -1e30f; l[r] = 0.f; }
#pragma unroll
  for (int n = 0; n < 4; ++n) outv[n] = (f32x4){0.f, 0.f, 0.f, 0.f};

  for (int i = 0; i < 16; ++i) {
    const int cur = i & 1;
    s8v nk, nv;
    const bool pf = (i < 15);
    if (pf) {
      const int kn = (i + 1) << 6;
      nk = *reinterpret_cast<const s8v*>(&kbase[(size_t)(kn + sr) * 64 + sc]);
      nv = *reinterpret_cast<const s8v*>(&vtbase[((size_t)sr << 10) + kn + sc]);
    }
    f32x4 sacc[4];
    __builtin_amdgcn_s_setprio(1);
#pragma unroll
    for (int n = 0; n < 4; ++n) {
      const bf16x8 kf0 = *reinterpret_cast<const bf16x8*>(&Ks[cur][n * 16 + fr][koff0]);
      const bf16x8 kf1 = *reinterpret_cast<const bf16x8*>(&Ks[cur][n * 16 + fr][32 + koff0]);
      sacc[n] = (f32x4){0.f, 0.f, 0.f, 0.f};
      sacc[n] = __builtin_amdgcn_mfma_f32_16x16x32_bf16(qf[0], kf0, sacc[n], 0, 0, 0);
      sacc[n] = __builtin_amdgcn_mfma_f32_16x16x32_bf16(qf[1], kf1, sacc[n], 0, 0, 0);
    }
    __builtin_amdgcn_s_setprio(0);
    float vm[4];
    bool ok = true;
#pragma unroll
    for (int r = 0; r < 4; ++r) {
      vm[r] = fmaxf(fmaxf(sacc[0][r], sacc[1][r]), fmaxf(sacc[2][r], sacc[3][r]));
      ok = ok && (vm[r] <= m[r] + 8.f);
    }
    if (__all(ok)) {
#pragma unroll
      for (int r = 0; r < 4; ++r) {
        const float p0 = __expf(sacc[0][r] - m[r]), p1 = __expf(sacc[1][r] - m[r]);
        const float p2 = __expf(sacc[2][r] - m[r]), p3 = __expf(sacc[3][r] - m[r]);
        l[r] += p0 + p1 + p2 + p3;
        const int qr = wl * 16 + (fg << 2) + r;
        Ps[a][qr][fr] = f2bf(p0);
        Ps[a][qr][16 + fr] = f2bf(p1);
        Ps[a][qr][32 + fr] = f2bf(p2);
        Ps[a][qr][48 + fr] = f2bf(p3);
      }
    } else {
#pragma unroll
      for (int r = 0; r < 4; ++r) {
        float rm = vm[r];
        rm = fmaxf(rm, __shfl_xor(rm, 1));
        rm = fmaxf(rm, __shfl_xor(rm, 2));
        rm = fmaxf(rm, __shfl_xor(rm, 4));
        rm = fmaxf(rm, __shfl_xor(rm, 8));
        const float nm = fmaxf(m[r], rm);
        const float al = __expf(m[r] - nm);
        m[r] = nm;
        const float p0 = __expf(sacc[0][r] - nm), p1 = __expf(sacc[1][r] - nm);
        const float p2 = __expf(sacc[2][r] - nm), p3 = __expf(sacc[3][r] - nm);
        l[r] = l[r] * al + (p0 + p1 + p2 + p3);
        outv[0][r] *= al; outv[1][r] *= al; outv[2][r] *= al; outv[3][r] *= al;
        const int qr = wl * 16 + (fg << 2) + r;
        Ps[a][qr][fr] = f2bf(p0);
        Ps[a][qr][16 + fr] = f2bf(p1);
        Ps[a][qr][32 + fr] = f2bf(p2);
        Ps[a][qr][48 + fr] = f2bf(p3);
      }
    }
    // PV: Ps rows wl*16..+15 of tile a are wave-private; same-wave DS ordering
    // makes reads safe without a barrier.
    __builtin_amdgcn_s_setprio(1);
    const bf16x8 pa0 = *reinterpret_cast<const bf16x8*>(&Ps[a][wl * 16 + fr][koff0]);
    const bf16x8 pa1 = *reinterpret_cast<const bf16x8*>(&Ps[a][wl * 16 + fr][32 + koff0]);
#pragma unroll
    for (int n = 0; n < 4; ++n) {
      const bf16x8 vf0 = *reinterpret_cast<const bf16x8*>(&VsT[cur][n * 16 + fr][koff0]);
      const bf16x8 vf1 = *reinterpret_cast<const bf16x8*>(&VsT[cur][n * 16 + fr][32 + koff0]);
      outv[n] = __builtin_amdgcn_mfma_f32_16x16x32_bf16(pa0, vf0, outv[n], 0, 0, 0);
      outv[n] = __builtin_amdgcn_mfma_f32_16x16x32_bf16(pa1, vf1, outv[n], 0, 0, 0);
    }
    __builtin_amdgcn_s_setprio(0);
    if (pf) {  // write next tile into the INACTIVE buffers (no reader conflict)
      *reinterpret_cast<s8v*>(&Ks[cur ^ 1][sr][sc]) = nk;
      *reinterpret_cast<s8v*>(&VsT[cur ^ 1][sr][sc]) = nv;
    }
    __syncthreads();  // publish next-tile buffers; current-tile reads all done
  }
#pragma unroll
  for (int r = 0; r < 4; ++r) {
    float L = l[r];
    L += __shfl_xor(L, 1);
    L += __shfl_xor(L, 2);
    L += __shfl_xor(L, 4);
    L += __shfl_xor(L, 8);
    const float inv = 1.f / L;
    const int t = t0 + a * 64 + wl * 16 + (fg << 2) + r;
    const size_t base = (((size_t)((b_ << 10) | t)) << 9) + (h_ << 6);
#pragma unroll
    for (int n = 0; n < 4; ++n)
      ctx[base + n * 16 + fr] = f2bf(outv[n][r] * inv);
  }
}

// ---------------------------------------------------------------------------
// LDS-tiled depthwise conv K=31 SAME + fused BN partial stats (f32).
// ---------------------------------------------------------------------------
__global__ __launch_bounds__(256) void dwconv_kernel(
    const short* __restrict__ in, const float* __restrict__ w,
    const float* __restrict__ bias, short* __restrict__ out,
    float* __restrict__ ps, float* __restrict__ pq) {
  __shared__ __align__(16) short tile[286 * 72];
  __shared__ float wlds[31 * 64];
  const int id = blockIdx.x;  // 512
  const int ct = id & 15, tt = (id >> 4) & 3;
  const size_t b = id >> 6;
  const int c0 = ct << 6, t0 = tt << 8;
  const int tid = threadIdx.x;
  for (int i = tid; i < 31 * 64; i += 256) {
    const int kk = i >> 6, c = i & 63;
    wlds[i] = w[kk * 1024 + c0 + c];
  }
  for (int i = tid; i < 286 * 8; i += 256) {
    const int row = i >> 3, seg = i & 7;
    const int gt = t0 - 15 + row;
    s8v val = {};
    if (gt >= 0 && gt < 1024)
      val = *reinterpret_cast<const s8v*>(&in[(b << 20) + ((size_t)gt << 10) + c0 + (seg << 3)]);
    *reinterpret_cast<s8v*>(&tile[row * 72 + (seg << 3)]) = val;
  }
  __syncthreads();
  const int cg = tid & 7, tg = tid >> 3;
  const int tl = tg << 3;
  float acc[8][8];
  const float4 b0 = *reinterpret_cast<const float4*>(&bias[c0 + (cg << 3)]);
  const float4 b1 = *reinterpret_cast<const float4*>(&bias[c0 + (cg << 3) + 4]);
#pragma unroll
  for (int t = 0; t < 8; ++t) {
    acc[t][0] = b0.x; acc[t][1] = b0.y; acc[t][2] = b0.z; acc[t][3] = b0.w;
    acc[t][4] = b1.x; acc[t][5] = b1.y; acc[t][6] = b1.z; acc[t][7] = b1.w;
  }
  for (int kk = 0; kk < 31; ++kk) {
    const float4 w0 = *reinterpret_cast<const float4*>(&wlds[kk * 64 + (cg << 3)]);
    const float4 w1 = *reinterpret_cast<const float4*>(&wlds[kk * 64 + (cg << 3) + 4]);
#pragma unroll
    for (int t = 0; t < 8; ++t) {
      const s8v xv = *reinterpret_cast<const s8v*>(&tile[(tl + t + kk) * 72 + (cg << 3)]);
      acc[t][0] = fmaf(bf2f(xv[0]), w0.x, acc[t][0]);
      acc[t][1] = fmaf(bf2f(xv[1]), w0.y, acc[t][1]);
      acc[t][2] = fmaf(bf2f(xv[2]), w0.z, acc[t][2]);
      acc[t][3] = fmaf(bf2f(xv[3]), w0.w, acc[t][3]);
      acc[t][4] = fmaf(bf2f(xv[4]), w1.x, acc[t][4]);
      acc[t][5] = fmaf(bf2f(xv[5]), w1.y, acc[t][5]);
      acc[t][6] = fmaf(bf2f(xv[6]), w1.z, acc[t][6]);
      acc[t][7] = fmaf(bf2f(xv[7]), w1.w, acc[t][7]);
    }
  }
#pragma unroll
  for (int t = 0; t < 8; ++t) {
    s8v o;
#pragma unroll
    for (int j = 0; j < 8; ++j) o[j] = f2bf(acc[t][j]);
    *reinterpret_cast<s8v*>(&out[(b << 20) + ((size_t)(t0 + tl + t) << 10) + c0 + (cg << 3)]) = o;
  }
  // ---- fused BN partial stats
  float s8_[8], q8_[8];
#pragma unroll
  for (int j = 0; j < 8; ++j) {
    float S = 0.f, Q = 0.f;
#pragma unroll
    for (int t = 0; t < 8; ++t) {
      S += acc[t][j];
      Q = fmaf(acc[t][j], acc[t][j], Q);
    }
    s8_[j] = S;
    q8_[j] = Q;
  }
  __syncthreads();
  float* fred = (float*)tile;
#pragma unroll
  for (int j = 0; j < 8; ++j) {
    fred[tid * 16 + j] = s8_[j];
    fred[tid * 16 + 8 + j] = q8_[j];
  }
  __syncthreads();
  if (tid < 64) {
    const int cg_ = tid >> 3, j_ = tid & 7;
    float S = 0.f, Q = 0.f;
    for (int tg_ = 0; tg_ < 32; ++tg_) {
      const int th = tg_ * 8 + cg_;
      S += fred[th * 16 + j_];
      Q += fred[th * 16 + 8 + j_];
    }
    const int pidx = ((int)b << 2) + tt;  // 0..31
    ps[pidx * 1024 + c0 + tid] = S;
    pq[pidx * 1024 + c0 + tid] = Q;
  }
}

// ---------------------------------------------------------------------------
// BN finalize (reduce 32 partials) + apply+swish.
// ---------------------------------------------------------------------------
__global__ __launch_bounds__(256) void bn_finalize_kernel(
    const float* __restrict__ ps, const float* __restrict__ pq, float* __restrict__ stats) {
  const int c = blockIdx.x * 256 + threadIdx.x;
  float s = 0.f, q = 0.f;
  for (int i = 0; i < 32; ++i) {
    s += ps[i * 1024 + c];
    q += pq[i * 1024 + c];
  }
  const float mean = s * (1.f / 8192.f);
  const float var = q * (1.f / 8192.f) - mean * mean;
  stats[c] = mean;
  stats[1024 + c] = rsqrtf(fmaxf(var, 0.f) + 1e-5f);
}

__global__ __launch_bounds__(256) void bn_apply_kernel(
    const short* __restrict__ y, const float* __restrict__ g, const float* __restrict__ b,
    const float* __restrict__ stats, short* __restrict__ out) {
  const size_t i = (size_t)blockIdx.x * 256 + threadIdx.x;
  const size_t f = i << 2;
  const int c = (int)(f & 1023);
  const s4v yv = *reinterpret_cast<const s4v*>(&y[f]);
  s4v o;
#pragma unroll
  for (int j = 0; j < 4; ++j) {
    const float v = (bf2f(yv[j]) - stats[c + j]) * stats[1024 + c + j] * g[c + j] + b[c + j];
    o[j] = f2bf(v * sigmoid_(v));
  }
  *reinterpret_cast<s4v*>(&out[f]) = o;
}

// ---------------------------------------------------------------------------
extern "C" void kernel_launch(void* const* d_in, const int* in_sizes, int n_in,
                              void* d_out, int out_size, void* d_ws, size_t ws_size,
                              hipStream_t stream) {
  const float* x        = (const float*)d_in[0];
  const float* ffn1_w1  = (const float*)d_in[1];
  const float* ffn1_b1  = (const float*)d_in[2];
  const float* ffn1_w2  = (const float*)d_in[3];
  const float* ffn1_b2  = (const float*)d_in[4];
  const float* ln_att_g = (const float*)d_in[5];
  const float* ln_att_b = (const float*)d_in[6];
  const float* wq       = (const float*)d_in[7];
  const float* bq       = (const float*)d_in[8];
  const float* wk       = (const float*)d_in[9];
  const float* bk       = (const float*)d_in[10];
  const float* wv       = (const float*)d_in[11];
  const float* bv       = (const float*)d_in[12];
  const float* wo_      = (const float*)d_in[13];
  const float* bo       = (const float*)d_in[14];
  const float* cln_g    = (const float*)d_in[15];
  const float* cln_b    = (const float*)d_in[16];
  const float* pw1_w    = (const float*)d_in[17];
  const float* pw1_b    = (const float*)d_in[18];
  const float* dw_w     = (const float*)d_in[19];
  const float* dw_b     = (const float*)d_in[20];
  const float* bn_g     = (const float*)d_in[21];
  const float* bn_b     = (const float*)d_in[22];
  const float* pw2_w    = (const float*)d_in[23];
  const float* pw2_b    = (const float*)d_in[24];
  const float* ffn2_w1  = (const float*)d_in[25];
  const float* ffn2_b1  = (const float*)d_in[26];
  const float* ffn2_w2  = (const float*)d_in[27];
  const float* ffn2_b2  = (const float*)d_in[28];
  const float* ln_out_g = (const float*)d_in[29];
  const float* ln_out_b = (const float*)d_in[30];

  char* wsb = (char*)d_ws;
  const size_t MB = 1u << 20;
  short* buf_y = (short*)(wsb);            // residual stream bf16 (8 MB)
  char* Bre = wsb + 16 * MB;
  short* qkv16 = (short*)(Bre);            // q,k (B,H,T,64) + v^T (B,H,64,T), 24 MB
  short* lnq  = (short*)(Bre + 48 * MB);
  short* ctx  = (short*)(Bre + 56 * MB);
  short* h1   = (short*)(Bre);
  short* xb   = (short*)(Bre + 16 * MB);
  short* gluo = (short*)(Bre);
  short* bno  = (short*)(Bre + 48 * MB);
  char* Cre = wsb + 80 * MB;
  short* lnc  = (short*)(Cre);
  short* dwo16= (short*)(Cre + 8 * MB);
  char* Dre = wsb + 112 * MB;
  short* w_f1w1 = (short*)(Dre);
  short* w_f1w2 = (short*)(Dre + 1 * MB);
  short* w_qkv  = (short*)(Dre + 2 * MB);
  short* w_wo   = (short*)(Dre + 3 * MB + 512 * 1024);
  short* w_pw1  = (short*)(Dre + 4 * MB);
  short* w_pw2  = (short*)(Dre + 6 * MB);
  short* w_f2w1 = (short*)(Dre + 7 * MB);
  short* w_f2w2 = (short*)(Dre + 8 * MB);
  float* bqkv   = (float*)(Dre + 9 * MB);
  float* ps     = (float*)(Dre + 9 * MB + 8192);
  float* pq     = (float*)(Dre + 10 * MB + 8192);
  float* stats  = (float*)(Dre + 11 * MB + 8192);
  float* rtbl   = (float*)(Dre + 12 * MB);

  const dim3 blk(256);

  // ---- single mega-prep
  prep_kernel<<<6022, blk, 0, stream>>>(
      x, xb, ffn1_w1, w_f1w1, ffn1_w2, w_f1w2, wq, wk, wv, w_qkv, wo_, w_wo,
      pw1_w, w_pw1, pw2_w, w_pw2, ffn2_w1, w_f2w1, ffn2_w2, w_f2w2,
      bq, bk, bv, bqkv, rtbl);

  // ---- FFN1: y = x + 0.5*(swish(x@w1+b1)@w2+b2)
  mgemm<64, 128, 64, 1, 512><<<dim3(8, 128), dim3(512), 0, stream>>>(xb, w_f1w1, ffn1_b1, nullptr, nullptr, h1, M_ROWS, 1024, 512);
  mgemm<64, 128, 64, 3, 512><<<dim3(4, 128), dim3(512), 0, stream>>>(h1, w_f1w2, ffn1_b2, nullptr, xb, buf_y, M_ROWS, 512, 1024);

  // ---- MHSA (QKV 8-wave with vstg aliased on smem)
  ln_kernel<short><<<2048, blk, 0, stream>>>(buf_y, ln_att_g, ln_att_b, lnq);
  mgemm<128, 128, 32, 4, 512><<<dim3(12, 64), dim3(512), 0, stream>>>(lnq, w_qkv, bqkv, rtbl, nullptr, qkv16, M_ROWS, 1536, 512);
  attn_mfma_kernel<<<512, dim3(512), 0, stream>>>(qkv16, qkv16 + 4194304, qkv16 + 8388608, ctx);
  mgemm<64, 128, 64, 2, 512><<<dim3(4, 128), dim3(512), 0, stream>>>(ctx, w_wo, bo, nullptr, buf_y, buf_y, M_ROWS, 512, 512);

  // ---- Conv module (pw1 -> 128x128 tiles, 1024 blocks = 4/CU; dwconv emits
  //      BN partial stats)
  ln_kernel<short><<<2048, blk, 0, stream>>>(buf_y, cln_g, cln_b, lnc);
  mgemm<128, 128, 32, 6, 512><<<dim3(16, 64), dim3(512), 0, stream>>>(lnc, w_pw1, pw1_b, nullptr, nullptr, gluo, M_ROWS, 2048, 512);
  dwconv_kernel<<<512, blk, 0, stream>>>(gluo, dw_w, dw_b, dwo16, ps, pq);
  bn_finalize_kernel<<<4, blk, 0, stream>>>(ps, pq, stats);
  bn_apply_kernel<<<8192, blk, 0, stream>>>(dwo16, bn_g, bn_b, stats, bno);
  mgemm<64, 128, 64, 2, 512><<<dim3(4, 128), dim3(512), 0, stream>>>(bno, w_pw2, pw2_b, nullptr, buf_y, buf_y, M_ROWS, 512, 1024);

  // ---- FFN2
  mgemm<64, 128, 64, 1, 512><<<dim3(8, 128), dim3(512), 0, stream>>>(buf_y, w_f2w1, ffn2_b1, nullptr, nullptr, h1, M_ROWS, 1024, 512);
  mgemm<64, 128, 64, 3, 512><<<dim3(4, 128), dim3(512), 0, stream>>>(h1, w_f2w2, ffn2_b2, nullptr, buf_y, buf_y, M_ROWS, 512, 1024);

  // ---- Final LN -> d_out (f32)
  ln_kernel<float><<<2048, blk, 0, stream>>>(buf_y, ln_out_g, ln_out_b, (float*)d_out);
}

// Round 24
// 243.011 us; speedup vs baseline: 1.0516x; 1.0193x over previous
//
#include <hip/hip_runtime.h>
#include <hip/hip_bf16.h>

// ---------------------------------------------------------------------------
// Conformer block: bf16-MFMA GEMMs (XCD-swizzled, counted-vmcnt; small GEMMs
// 64x128x64 XOR-swizzled 8-wave; QKV 128x128x32 / pw1 128x256x32 8-wave, vstg
// aliased on smem) + bf16-MFMA flash attention (128 q-rows, 8 waves, dbuf K/V,
// 1 barrier/tile, k-permuted P/V layout -> vector Ps stores) + LDS-tiled
// depthwise conv with fused BN stats + wave-per-row LN + mega-prep.
// B=8, T=1024, D=512, HID=1024, C=1024, K=31, H=8, dh=64.  M = B*T = 8192.
// ---------------------------------------------------------------------------

#define M_ROWS 8192

using bf16x8 = __attribute__((ext_vector_type(8))) short;
using f32x4  = __attribute__((ext_vector_type(4))) float;
using s8v    = __attribute__((ext_vector_type(8))) short;
using s4v    = __attribute__((ext_vector_type(4))) short;

__device__ __forceinline__ float sigmoid_(float v) { return 1.f / (1.f + expf(-v)); }

__device__ __forceinline__ float bf2f(short s) {
  return __uint_as_float(((unsigned)(unsigned short)s) << 16);
}
__device__ __forceinline__ short f2bf(float f) {
  __hip_bfloat16 h = __float2bfloat16(f);
  return *reinterpret_cast<short*>(&h);
}

__device__ __forceinline__ void gl16(const void* g, void* l) {
  __builtin_amdgcn_global_load_lds((const __attribute__((address_space(1))) void*)g,
                                   (__attribute__((address_space(3))) void*)l, 16, 0, 0);
}

// ---------------------------------------------------------------------------
// bf16 MFMA GEMM: outb[M,N] = epi(A[M,K] @ Bt[N,K]^T + bias).
// BK=32: linear LDS. BK=64: XOR-swizzled (linear LDS dest + inverse-swizzled
// GLOBAL source + same XOR on frag read). Counted-vmcnt 2-buffer K-loop.
// Single smem[] holds As|Bs; EPI4's v^T staging buffer ALIASES smem (only
// used after the K-loop, behind a barrier).
// EPI: 1 swish->bf16 | 2 resb+acc+bias->bf16 | 3 resb+0.5*(acc+bias)->bf16
//      4 QKV: table-RoPE q/k ->bf16 (B,H,T,64); v->bf16 (B,H,64,T') where T'
//             is k-permuted within each 64-block: t' = 4*(t&15) + ((t>>4)&3)
//      6 pw1+GLU (packed weights): a*sigmoid(gate)->bf16
// ---------------------------------------------------------------------------
template <int BM, int BN, int BK, int EPI, int THREADS>
__global__ __launch_bounds__(THREADS) void mgemm(
    const short* __restrict__ A, const short* __restrict__ Bt,
    const float* __restrict__ bias, const float* __restrict__ res,
    const short* __restrict__ resb, short* __restrict__ outb, int M, int N, int K) {
  constexpr int NW = THREADS / 64;         // waves per block
  constexpr int WR = BM / 64;              // wave-grid rows
  constexpr int WC = NW / WR;              // wave-grid cols
  constexpr int NF = BN / (16 * WC);       // N-frags per wave
  constexpr int CPW = BN / WC;             // cols per wave
  constexpr int KH = BK / 32;
  constexpr int RPP = THREADS / (BK / 8);  // rows staged per pass
  constexpr int APASS = BM / RPP;
  constexpr int BPASS = BN / RPP;
  constexpr int LPS = APASS + BPASS;       // loads per stage per thread
  __shared__ __align__(16) short smem[2 * BM * BK + 2 * BN * BK];
  short* As0 = smem;
  short* Bs0 = smem + 2 * BM * BK;
  const int tid = threadIdx.x;
  const int lane = tid & 63, wid = tid >> 6;
  const int wr = wid / WC, wc = wid % WC;
  const int nbx = gridDim.x;
  const int nwg = nbx * gridDim.y;
  int id = blockIdx.y * nbx + blockIdx.x;
  id = (id & 7) * (nwg >> 3) + (id >> 3);
  const int bm = (id / nbx) * BM;
  const int bn = (id % nbx) * BN;
  f32x4 acc[4][NF];
#pragma unroll
  for (int m = 0; m < 4; ++m)
#pragma unroll
    for (int n = 0; n < NF; ++n) acc[m][n] = (f32x4){0.f, 0.f, 0.f, 0.f};
  const short* Ablk = A + (size_t)bm * K;
  const short* Bblk = Bt + (size_t)bn * K;
  const int jl = tid & (BK / 8 - 1);
  const int r0 = tid / (BK / 8);
  const int ks = ((BK == 64) ? (jl ^ (r0 & 7)) : jl) << 3;
#define STAGE(buf, k0)                                                                 \
  do {                                                                                 \
    _Pragma("unroll")                                                                  \
    for (int p = 0; p < APASS; ++p)                                                    \
      gl16(Ablk + (size_t)(r0 + p * RPP) * K + (k0) + ks,                              \
           (char*)(As0 + (buf) * BM * BK) + p * (THREADS * 16) + wid * 1024);          \
    _Pragma("unroll")                                                                  \
    for (int p = 0; p < BPASS; ++p)                                                    \
      gl16(Bblk + (size_t)(r0 + p * RPP) * K + (k0) + ks,                              \
           (char*)(Bs0 + (buf) * BN * BK) + p * (THREADS * 16) + wid * 1024);          \
  } while (0)

  STAGE(0, 0);
  STAGE(1, BK);
  const int NS = K / BK;
  const int fr = lane & 15, fg = lane >> 4;
  const int arow = wr * 64 + fr;
  const int brow = wc * CPW + fr;
  for (int i = 0; i < NS; ++i) {
    if (i + 1 < NS) {
      if constexpr (LPS == 6)      asm volatile("s_waitcnt vmcnt(6)" ::: "memory");
      else if constexpr (LPS == 4) asm volatile("s_waitcnt vmcnt(4)" ::: "memory");
      else if constexpr (LPS == 3) asm volatile("s_waitcnt vmcnt(3)" ::: "memory");
      else                         asm volatile("s_waitcnt vmcnt(2)" ::: "memory");
    } else {
      asm volatile("s_waitcnt vmcnt(0)" ::: "memory");
    }
    __builtin_amdgcn_s_barrier();
    asm volatile("" ::: "memory");
    const int cur = i & 1;
    bf16x8 af[KH][4], bfr[KH][NF];
#pragma unroll
    for (int kk = 0; kk < KH; ++kk) {
      const int cx = (BK == 64) ? (((((kk << 2) + fg)) ^ (fr & 7)) << 3)
                                : ((fg << 3) + kk * 32);
#pragma unroll
      for (int m = 0; m < 4; ++m)
        af[kk][m] = *reinterpret_cast<const bf16x8*>(
            &As0[cur * BM * BK + (arow + m * 16) * BK + cx]);
#pragma unroll
      for (int n = 0; n < NF; ++n)
        bfr[kk][n] = *reinterpret_cast<const bf16x8*>(
            &Bs0[cur * BN * BK + (brow + n * 16) * BK + cx]);
    }
    asm volatile("s_waitcnt lgkmcnt(0)" ::: "memory");
    __builtin_amdgcn_s_barrier();
    if ((i + 2) * BK < K) STAGE(cur, (i + 2) * BK);
#pragma unroll
    for (int kk = 0; kk < KH; ++kk)
#pragma unroll
      for (int m = 0; m < 4; ++m)
#pragma unroll
        for (int n = 0; n < NF; ++n)
          acc[m][n] = __builtin_amdgcn_mfma_f32_16x16x32_bf16(af[kk][m], bfr[kk][n],
                                                              acc[m][n], 0, 0, 0);
  }
#undef STAGE
  const int orow0 = bm + wr * 64 + ((lane >> 4) << 2);
  const int ocol0 = bn + wc * CPW + fr;

  if constexpr (EPI == 4) {
    const int sel = bn >> 9;
    const float2* tbl = (const float2*)res;  // [1024][32] (cos,sin)
    if (sel == 2) {
      // v^T staging buffer aliases smem (safe: first use is behind a barrier).
      // Store index k-PERMUTED within each 64-row block: t' = 4*(t&15)+(t>>4).
      short* vstg = smem;  // needs 64*132 = 8448 shorts <= smem size
      const int b_ = bm >> 10, t0v = bm & 1023;
      const int hb = (bn & 511) >> 6;
#pragma unroll
      for (int pass = 0; pass < 2; ++pass) {
        __syncthreads();
        if (((wc * CPW) >> 6) == pass) {
          const int dlb = (wc * CPW) & 63;
#pragma unroll
          for (int m = 0; m < 4; ++m) {
            const int rl = wr * 64 + ((lane >> 4) << 2) + m * 16;
#pragma unroll
            for (int n = 0; n < NF; ++n) {
              const int dl = dlb + n * 16 + fr;
              const float bv = bias[bn + pass * 64 + dl];
#pragma unroll
              for (int r = 0; r < 4; ++r) {
                const int t128 = rl + r;
                const int t64 = t128 & 63;
                const int tp = (t128 & 64) | ((t64 & 15) << 2) | (t64 >> 4);
                vstg[dl * 132 + tp] = f2bf(acc[m][n][r] + bv);
              }
            }
          }
        }
        __syncthreads();
        for (int c = tid; c < 1024; c += THREADS) {
          const int d = c >> 4, t8 = (c & 15) << 3;
          const s8v val = *reinterpret_cast<const s8v*>(&vstg[d * 132 + t8]);
          *reinterpret_cast<s8v*>(
              &outb[(size_t)8388608 + (((size_t)((b_ << 3) + hb + pass)) << 16) +
                    ((size_t)d << 10) + t0v + t8]) = val;
        }
      }
    } else {
      const float qsc = (sel == 0) ? 0.04419417382415922f : 1.f;  // 1/sqrt(512)
#pragma unroll
      for (int n = 0; n < NF; ++n) {
        const int col = ocol0 + n * 16;
        const int h = (col >> 6) & 7, d = col & 63;
        const int p = d >> 1;
        const float bv = bias[col];
#pragma unroll
        for (int m = 0; m < 4; ++m) {
#pragma unroll
          for (int r = 0; r < 4; ++r) {
            const int row = orow0 + m * 16 + r;
            const int b_ = row >> 10, t_ = row & 1023;
            const int pos = (sel == 0) ? h : t_;
            const float2 cs = tbl[pos * 32 + p];
            float vv = acc[m][n][r] + bv;
            const float pv = __shfl_xor(vv, 1);
            float o = ((lane & 1) == 0) ? (vv * cs.x - pv * cs.y) : (vv * cs.x + pv * cs.y);
            outb[(size_t)sel * 4194304 + (((size_t)((b_ << 3) + h)) << 16) + ((size_t)t_ << 6) + d] =
                f2bf(o * qsc);
          }
        }
      }
    }
  } else if constexpr (EPI == 6) {
    // Packed GLU epilogue, generic: per frag-pair (2np,2np+1) = (a,gate).
#pragma unroll
    for (int m = 0; m < 4; ++m) {
#pragma unroll
      for (int np = 0; np < NF / 2; ++np) {
        const int colbase = bn + wc * CPW + ((2 * np) << 4);
        const int j = colbase >> 7;
        const int u = (colbase >> 5) & 3;
        const int gc = (j << 6) + (u << 4) + fr;
        const float ba = bias[gc];
        const float bg = bias[1024 + gc];
#pragma unroll
        for (int r = 0; r < 4; ++r) {
          const int row = orow0 + m * 16 + r;
          const float a = acc[m][2 * np][r] + ba;
          const float g = acc[m][2 * np + 1][r] + bg;
          outb[(size_t)row * 1024 + gc] = f2bf(a * sigmoid_(g));
        }
      }
    }
  } else {
#pragma unroll
    for (int m = 0; m < 4; ++m) {
#pragma unroll
      for (int n = 0; n < NF; ++n) {
        const int col = ocol0 + n * 16;
        const float bv = bias[col];
#pragma unroll
        for (int r = 0; r < 4; ++r) {
          const int row = orow0 + m * 16 + r;
          float v = acc[m][n][r] + bv;
          if constexpr (EPI == 1) {
            v = v * sigmoid_(v);
          } else if constexpr (EPI == 2) {
            v += bf2f(resb[(size_t)row * N + col]);
          } else if constexpr (EPI == 3) {
            v = bf2f(resb[(size_t)row * N + col]) + 0.5f * v;
          }
          outb[(size_t)row * N + col] = f2bf(v);
        }
      }
    }
  }
}

// ---------------------------------------------------------------------------
// MEGA-PREP: all weight casts/transposes/packs + bias concat + rope table.
// ---------------------------------------------------------------------------
__device__ __forceinline__ void dev_cast8(const float* in, short* out, int i) {
  const float4 a = *reinterpret_cast<const float4*>(&in[(size_t)i * 8]);
  const float4 b = *reinterpret_cast<const float4*>(&in[(size_t)i * 8 + 4]);
  s8v o = { f2bf(a.x), f2bf(a.y), f2bf(a.z), f2bf(a.w),
            f2bf(b.x), f2bf(b.y), f2bf(b.z), f2bf(b.w) };
  *reinterpret_cast<s8v*>(&out[(size_t)i * 8]) = o;
}

__global__ __launch_bounds__(256) void prep_kernel(
    const float* __restrict__ x, short* __restrict__ xb,
    const float* __restrict__ f1w1, short* __restrict__ wf1w1,
    const float* __restrict__ f1w2, short* __restrict__ wf1w2,
    const float* __restrict__ wq, const float* __restrict__ wk,
    const float* __restrict__ wv, short* __restrict__ wqkv,
    const float* __restrict__ wo, short* __restrict__ wwo,
    const float* __restrict__ pw1, short* __restrict__ wpw1,
    const float* __restrict__ pw2, short* __restrict__ wpw2,
    const float* __restrict__ f2w1, short* __restrict__ wf2w1,
    const float* __restrict__ f2w2, short* __restrict__ wf2w2,
    const float* __restrict__ bq, const float* __restrict__ bk,
    const float* __restrict__ bv, float* __restrict__ bqkv,
    float* __restrict__ rtbl) {
  __shared__ float t[32][33];
  const int blk = blockIdx.x, tid = threadIdx.x;
  const float* tin = nullptr;
  short* tout = nullptr;
  int tK = 0, tN = 0, tr = 0, tnbx = 0;
  if (blk < 2048) {
    dev_cast8(x, xb, blk * 256 + tid);
    return;
  } else if (blk < 2560) { tin = f1w1; tout = wf1w1; tK = 512; tN = 1024; tr = blk - 2048; tnbx = 32; }
  else if (blk < 3072)   { tin = f1w2; tout = wf1w2; tK = 1024; tN = 512; tr = blk - 2560; tnbx = 16; }
  else if (blk < 3328)   { tin = wq; tout = wqkv; tK = 512; tN = 512; tr = blk - 3072; tnbx = 16; }
  else if (blk < 3584)   { tin = wk; tout = wqkv + 512 * 512; tK = 512; tN = 512; tr = blk - 3328; tnbx = 16; }
  else if (blk < 3840)   { tin = wv; tout = wqkv + 1024 * 512; tK = 512; tN = 512; tr = blk - 3584; tnbx = 16; }
  else if (blk < 4096)   { tin = wo; tout = wwo; tK = 512; tN = 512; tr = blk - 3840; tnbx = 16; }
  else if (blk < 4608) {
    const int idx = (blk - 4096) * 256 + tid;
    const int pc = idx >> 6, kk = (idx & 63) << 3;
    const int j = pc >> 7, s = (pc >> 4) & 7, fr = pc & 15;
    const int oc = ((s & 1) << 10) + (j << 6) + ((s >> 1) << 4) + fr;
    const float4 a = *reinterpret_cast<const float4*>(&pw1[(size_t)oc * 512 + kk]);
    const float4 b = *reinterpret_cast<const float4*>(&pw1[(size_t)oc * 512 + kk + 4]);
    s8v o = { f2bf(a.x), f2bf(a.y), f2bf(a.z), f2bf(a.w),
              f2bf(b.x), f2bf(b.y), f2bf(b.z), f2bf(b.w) };
    *reinterpret_cast<s8v*>(&wpw1[(size_t)pc * 512 + kk]) = o;
    return;
  } else if (blk < 4864) {
    dev_cast8(pw2, wpw2, (blk - 4608) * 256 + tid);
    return;
  } else if (blk < 5376) { tin = f2w1; tout = wf2w1; tK = 512; tN = 1024; tr = blk - 4864; tnbx = 32; }
  else if (blk < 5888)   { tin = f2w2; tout = wf2w2; tK = 1024; tN = 512; tr = blk - 5376; tnbx = 16; }
  else if (blk < 6016) {
    const int i = (blk - 5888) * 256 + tid;  // 32768
    const int tt = i >> 5, p = i & 31;
    const float inv = exp2f(-(float)p * 0.41524101186092f);
    float s, c;
    sincosf((float)tt * inv, &s, &c);
    rtbl[i * 2] = c;
    rtbl[i * 2 + 1] = s;
    return;
  } else {
    const int i = (blk - 6016) * 256 + tid;
    if (i < 1536) bqkv[i] = i < 512 ? bq[i] : (i < 1024 ? bk[i - 512] : bv[i - 1024]);
    return;
  }
  const int n0 = (tr % tnbx) << 5, k0 = (tr / tnbx) << 5;
  const int tx = tid & 31, ty = tid >> 5;
  for (int r = ty; r < 32; r += 8) t[r][tx] = tin[(size_t)(k0 + r) * tN + n0 + tx];
  __syncthreads();
  for (int r = ty; r < 32; r += 8) tout[(size_t)(n0 + r) * tK + k0 + tx] = f2bf(t[tx][r]);
}

// ---------------------------------------------------------------------------
// LayerNorm over last dim (512), bf16 input. One WAVE per row (4 rows/block).
// ---------------------------------------------------------------------------
template <typename OT>
__global__ __launch_bounds__(256) void ln_kernel(
    const short* __restrict__ in, const float* __restrict__ g,
    const float* __restrict__ b, OT* __restrict__ out) {
  const int tid = threadIdx.x, lane = tid & 63;
  const size_t row = ((size_t)blockIdx.x << 2) + (tid >> 6);
  const int c0 = lane << 3;
  const s8v v = *reinterpret_cast<const s8v*>(&in[(row << 9) + c0]);
  float f[8];
  float s = 0.f;
#pragma unroll
  for (int j = 0; j < 8; ++j) { f[j] = bf2f(v[j]); s += f[j]; }
  for (int o = 32; o; o >>= 1) s += __shfl_xor(s, o);
  const float mean = s * (1.f / 512.f);
  float d[8];
  float q = 0.f;
#pragma unroll
  for (int j = 0; j < 8; ++j) { d[j] = f[j] - mean; q = fmaf(d[j], d[j], q); }
  for (int o = 32; o; o >>= 1) q += __shfl_xor(q, o);
  const float inv = rsqrtf(q * (1.f / 512.f) + 1e-5f);
  const float4 g0 = *reinterpret_cast<const float4*>(&g[c0]);
  const float4 g1 = *reinterpret_cast<const float4*>(&g[c0 + 4]);
  const float4 b0 = *reinterpret_cast<const float4*>(&b[c0]);
  const float4 b1 = *reinterpret_cast<const float4*>(&b[c0 + 4]);
  const float gg[8] = {g0.x, g0.y, g0.z, g0.w, g1.x, g1.y, g1.z, g1.w};
  const float bb[8] = {b0.x, b0.y, b0.z, b0.w, b1.x, b1.y, b1.z, b1.w};
  if constexpr (sizeof(OT) == 2) {
    s8v o;
#pragma unroll
    for (int j = 0; j < 8; ++j) o[j] = f2bf(d[j] * inv * gg[j] + bb[j]);
    *reinterpret_cast<s8v*>(&out[(row << 9) + c0]) = o;
  } else {
    float4 o0, o1;
    o0.x = d[0] * inv * gg[0] + bb[0]; o0.y = d[1] * inv * gg[1] + bb[1];
    o0.z = d[2] * inv * gg[2] + bb[2]; o0.w = d[3] * inv * gg[3] + bb[3];
    o1.x = d[4] * inv * gg[4] + bb[4]; o1.y = d[5] * inv * gg[5] + bb[5];
    o1.z = d[6] * inv * gg[6] + bb[6]; o1.w = d[7] * inv * gg[7] + bb[7];
    *reinterpret_cast<float4*>(&out[(row << 9) + c0]) = o0;
    *reinterpret_cast<float4*>(&out[(row << 9) + c0 + 4]) = o1;
  }
}

// ---------------------------------------------------------------------------
// MFMA flash attention: one block = 8 WAVES (512 threads) per (b,h,128-q-rows)
// -> 512 blocks, XCD-swizzled. Waves 0-3 own q-tile A, waves 4-7 q-tile B.
// Double-buffered K/V LDS -> 1 barrier per KV tile (Ps is wave-private).
// V arrives k-PERMUTED within each 64-key block (kv' = 4*(kv&15)+(kv>>4)),
// so the 4 P values per (row,fr) pack into ONE ds_write_b64 at col fr*4.
// Async K/V reg-prefetch; defer-max (THR=8); setprio around MFMA clusters.
// ---------------------------------------------------------------------------
__global__ __launch_bounds__(512) void attn_mfma_kernel(
    const short* __restrict__ q, const short* __restrict__ k,
    const short* __restrict__ vt, short* __restrict__ ctx) {
  __shared__ __align__(16) short Ks[2][64][72];
  __shared__ __align__(16) short VsT[2][64][72];
  __shared__ __align__(16) short Ps[2][64][72];  // also Q staging (128*72)
  const int bx = ((blockIdx.x & 7) << 6) | (blockIdx.x >> 3);  // nwg=512, cpx=64
  const int bh = bx >> 3, qt = bx & 7;
  const int b_ = bh >> 3, h_ = bh & 7;
  const int tid = threadIdx.x, lane = tid & 63, w = tid >> 6;
  const int a = w >> 2, wl = w & 3;
  const int t0 = qt << 7;  // 128 q-rows per block
  const short* qbase = q + ((size_t)bh << 16) + ((size_t)t0 << 6);
  const short* kbase = k + ((size_t)bh << 16);
  const short* vtbase = vt + ((size_t)bh << 16);
  const int sr = tid >> 3, sc = (tid & 7) << 3;  // staging: row 0..63, col chunk
  short* Qtmp = &Ps[0][0][0];
  // ---- stage Q (128 rows into Ps area) + K/V tile 0
  {
#pragma unroll
    for (int j = 0; j < 2; ++j) {
      const int idx = j * 512 + tid;
      const int qr_ = idx >> 3, qc = (idx & 7) << 3;
      const s8v v = *reinterpret_cast<const s8v*>(&qbase[(size_t)qr_ * 64 + qc]);
      *reinterpret_cast<s8v*>(&Qtmp[qr_ * 72 + qc]) = v;
    }
    const s8v k0v = *reinterpret_cast<const s8v*>(&kbase[(size_t)sr * 64 + sc]);
    *reinterpret_cast<s8v*>(&Ks[0][sr][sc]) = k0v;
    const s8v v0v = *reinterpret_cast<const s8v*>(&vtbase[((size_t)sr << 10) + sc]);
    *reinterpret_cast<s8v*>(&VsT[0][sr][sc]) = v0v;
  }
  __syncthreads();
  const int fr = lane & 15, fg = lane >> 4;
  const int koff0 = fg << 3;
  bf16x8 qf[2];
  qf[0] = *reinterpret_cast<const bf16x8*>(&Qtmp[(a * 64 + wl * 16 + fr) * 72 + koff0]);
  qf[1] = *reinterpret_cast<const bf16x8*>(&Qtmp[(a * 64 + wl * 16 + fr) * 72 + 32 + koff0]);
  __syncthreads();  // all Q reads done before Ps overwrite
  float m[4], l[4];
  f32x4 outv[4];
#pragma unroll
  for (int r = 0; r < 4; ++r) { m[r] = -1e30f; l[r] = 0.f; }
#pragma unroll
  for (int n = 0; n < 4; ++n) outv[n] = (f32x4){0.f, 0.f, 0.f, 0.f};

  for (int i = 0; i < 16; ++i) {
    const int cur = i & 1;
    s8v nk, nv;
    const bool pf = (i < 15);
    if (pf) {
      const int kn = (i + 1) << 6;
      nk = *reinterpret_cast<const s8v*>(&kbase[(size_t)(kn + sr) * 64 + sc]);
      nv = *reinterpret_cast<const s8v*>(&vtbase[((size_t)sr << 10) + kn + sc]);
    }
    f32x4 sacc[4];
    __builtin_amdgcn_s_setprio(1);
#pragma unroll
    for (int n = 0; n < 4; ++n) {
      const bf16x8 kf0 = *reinterpret_cast<const bf16x8*>(&Ks[cur][n * 16 + fr][koff0]);
      const bf16x8 kf1 = *reinterpret_cast<const bf16x8*>(&Ks[cur][n * 16 + fr][32 + koff0]);
      sacc[n] = (f32x4){0.f, 0.f, 0.f, 0.f};
      sacc[n] = __builtin_amdgcn_mfma_f32_16x16x32_bf16(qf[0], kf0, sacc[n], 0, 0, 0);
      sacc[n] = __builtin_amdgcn_mfma_f32_16x16x32_bf16(qf[1], kf1, sacc[n], 0, 0, 0);
    }
    __builtin_amdgcn_s_setprio(0);
    float vm[4];
    bool ok = true;
#pragma unroll
    for (int r = 0; r < 4; ++r) {
      vm[r] = fmaxf(fmaxf(sacc[0][r], sacc[1][r]), fmaxf(sacc[2][r], sacc[3][r]));
      ok = ok && (vm[r] <= m[r] + 8.f);
    }
    if (__all(ok)) {
#pragma unroll
      for (int r = 0; r < 4; ++r) {
        const float p0 = __expf(sacc[0][r] - m[r]), p1 = __expf(sacc[1][r] - m[r]);
        const float p2 = __expf(sacc[2][r] - m[r]), p3 = __expf(sacc[3][r] - m[r]);
        l[r] += p0 + p1 + p2 + p3;
        const int qr = wl * 16 + (fg << 2) + r;
        s4v pp = { f2bf(p0), f2bf(p1), f2bf(p2), f2bf(p3) };
        *reinterpret_cast<s4v*>(&Ps[a][qr][fr << 2]) = pp;
      }
    } else {
#pragma unroll
      for (int r = 0; r < 4; ++r) {
        float rm = vm[r];
        rm = fmaxf(rm, __shfl_xor(rm, 1));
        rm = fmaxf(rm, __shfl_xor(rm, 2));
        rm = fmaxf(rm, __shfl_xor(rm, 4));
        rm = fmaxf(rm, __shfl_xor(rm, 8));
        const float nm = fmaxf(m[r], rm);
        const float al = __expf(m[r] - nm);
        m[r] = nm;
        const float p0 = __expf(sacc[0][r] - nm), p1 = __expf(sacc[1][r] - nm);
        const float p2 = __expf(sacc[2][r] - nm), p3 = __expf(sacc[3][r] - nm);
        l[r] = l[r] * al + (p0 + p1 + p2 + p3);
        outv[0][r] *= al; outv[1][r] *= al; outv[2][r] *= al; outv[3][r] *= al;
        const int qr = wl * 16 + (fg << 2) + r;
        s4v pp = { f2bf(p0), f2bf(p1), f2bf(p2), f2bf(p3) };
        *reinterpret_cast<s4v*>(&Ps[a][qr][fr << 2]) = pp;
      }
    }
    // PV: Ps rows wl*16..+15 of tile a are wave-private; same-wave DS ordering
    // makes reads safe without a barrier. Both Ps cols and VsT cols are in
    // kv'-permuted order, so the contraction is unchanged.
    __builtin_amdgcn_s_setprio(1);
    const bf16x8 pa0 = *reinterpret_cast<const bf16x8*>(&Ps[a][wl * 16 + fr][koff0]);
    const bf16x8 pa1 = *reinterpret_cast<const bf16x8*>(&Ps[a][wl * 16 + fr][32 + koff0]);
#pragma unroll
    for (int n = 0; n < 4; ++n) {
      const bf16x8 vf0 = *reinterpret_cast<const bf16x8*>(&VsT[cur][n * 16 + fr][koff0]);
      const bf16x8 vf1 = *reinterpret_cast<const bf16x8*>(&VsT[cur][n * 16 + fr][32 + koff0]);
      outv[n] = __builtin_amdgcn_mfma_f32_16x16x32_bf16(pa0, vf0, outv[n], 0, 0, 0);
      outv[n] = __builtin_amdgcn_mfma_f32_16x16x32_bf16(pa1, vf1, outv[n], 0, 0, 0);
    }
    __builtin_amdgcn_s_setprio(0);
    if (pf) {  // write next tile into the INACTIVE buffers (no reader conflict)
      *reinterpret_cast<s8v*>(&Ks[cur ^ 1][sr][sc]) = nk;
      *reinterpret_cast<s8v*>(&VsT[cur ^ 1][sr][sc]) = nv;
    }
    __syncthreads();  // publish next-tile buffers; current-tile reads all done
  }
#pragma unroll
  for (int r = 0; r < 4; ++r) {
    float L = l[r];
    L += __shfl_xor(L, 1);
    L += __shfl_xor(L, 2);
    L += __shfl_xor(L, 4);
    L += __shfl_xor(L, 8);
    const float inv = 1.f / L;
    const int t = t0 + a * 64 + wl * 16 + (fg << 2) + r;
    const size_t base = (((size_t)((b_ << 10) | t)) << 9) + (h_ << 6);
#pragma unroll
    for (int n = 0; n < 4; ++n)
      ctx[base + n * 16 + fr] = f2bf(outv[n][r] * inv);
  }
}

// ---------------------------------------------------------------------------
// LDS-tiled depthwise conv K=31 SAME + fused BN partial stats (f32).
// ---------------------------------------------------------------------------
__global__ __launch_bounds__(256) void dwconv_kernel(
    const short* __restrict__ in, const float* __restrict__ w,
    const float* __restrict__ bias, short* __restrict__ out,
    float* __restrict__ ps, float* __restrict__ pq) {
  __shared__ __align__(16) short tile[286 * 72];
  __shared__ float wlds[31 * 64];
  const int id = blockIdx.x;  // 512
  const int ct = id & 15, tt = (id >> 4) & 3;
  const size_t b = id >> 6;
  const int c0 = ct << 6, t0 = tt << 8;
  const int tid = threadIdx.x;
  for (int i = tid; i < 31 * 64; i += 256) {
    const int kk = i >> 6, c = i & 63;
    wlds[i] = w[kk * 1024 + c0 + c];
  }
  for (int i = tid; i < 286 * 8; i += 256) {
    const int row = i >> 3, seg = i & 7;
    const int gt = t0 - 15 + row;
    s8v val = {};
    if (gt >= 0 && gt < 1024)
      val = *reinterpret_cast<const s8v*>(&in[(b << 20) + ((size_t)gt << 10) + c0 + (seg << 3)]);
    *reinterpret_cast<s8v*>(&tile[row * 72 + (seg << 3)]) = val;
  }
  __syncthreads();
  const int cg = tid & 7, tg = tid >> 3;
  const int tl = tg << 3;
  float acc[8][8];
  const float4 b0 = *reinterpret_cast<const float4*>(&bias[c0 + (cg << 3)]);
  const float4 b1 = *reinterpret_cast<const float4*>(&bias[c0 + (cg << 3) + 4]);
#pragma unroll
  for (int t = 0; t < 8; ++t) {
    acc[t][0] = b0.x; acc[t][1] = b0.y; acc[t][2] = b0.z; acc[t][3] = b0.w;
    acc[t][4] = b1.x; acc[t][5] = b1.y; acc[t][6] = b1.z; acc[t][7] = b1.w;
  }
  for (int kk = 0; kk < 31; ++kk) {
    const float4 w0 = *reinterpret_cast<const float4*>(&wlds[kk * 64 + (cg << 3)]);
    const float4 w1 = *reinterpret_cast<const float4*>(&wlds[kk * 64 + (cg << 3) + 4]);
#pragma unroll
    for (int t = 0; t < 8; ++t) {
      const s8v xv = *reinterpret_cast<const s8v*>(&tile[(tl + t + kk) * 72 + (cg << 3)]);
      acc[t][0] = fmaf(bf2f(xv[0]), w0.x, acc[t][0]);
      acc[t][1] = fmaf(bf2f(xv[1]), w0.y, acc[t][1]);
      acc[t][2] = fmaf(bf2f(xv[2]), w0.z, acc[t][2]);
      acc[t][3] = fmaf(bf2f(xv[3]), w0.w, acc[t][3]);
      acc[t][4] = fmaf(bf2f(xv[4]), w1.x, acc[t][4]);
      acc[t][5] = fmaf(bf2f(xv[5]), w1.y, acc[t][5]);
      acc[t][6] = fmaf(bf2f(xv[6]), w1.z, acc[t][6]);
      acc[t][7] = fmaf(bf2f(xv[7]), w1.w, acc[t][7]);
    }
  }
#pragma unroll
  for (int t = 0; t < 8; ++t) {
    s8v o;
#pragma unroll
    for (int j = 0; j < 8; ++j) o[j] = f2bf(acc[t][j]);
    *reinterpret_cast<s8v*>(&out[(b << 20) + ((size_t)(t0 + tl + t) << 10) + c0 + (cg << 3)]) = o;
  }
  // ---- fused BN partial stats
  float s8_[8], q8_[8];
#pragma unroll
  for (int j = 0; j < 8; ++j) {
    float S = 0.f, Q = 0.f;
#pragma unroll
    for (int t = 0; t < 8; ++t) {
      S += acc[t][j];
      Q = fmaf(acc[t][j], acc[t][j], Q);
    }
    s8_[j] = S;
    q8_[j] = Q;
  }
  __syncthreads();
  float* fred = (float*)tile;
#pragma unroll
  for (int j = 0; j < 8; ++j) {
    fred[tid * 16 + j] = s8_[j];
    fred[tid * 16 + 8 + j] = q8_[j];
  }
  __syncthreads();
  if (tid < 64) {
    const int cg_ = tid >> 3, j_ = tid & 7;
    float S = 0.f, Q = 0.f;
    for (int tg_ = 0; tg_ < 32; ++tg_) {
      const int th = tg_ * 8 + cg_;
      S += fred[th * 16 + j_];
      Q += fred[th * 16 + 8 + j_];
    }
    const int pidx = ((int)b << 2) + tt;  // 0..31
    ps[pidx * 1024 + c0 + tid] = S;
    pq[pidx * 1024 + c0 + tid] = Q;
  }
}

// ---------------------------------------------------------------------------
// BN finalize (reduce 32 partials) + apply+swish.
// ---------------------------------------------------------------------------
__global__ __launch_bounds__(256) void bn_finalize_kernel(
    const float* __restrict__ ps, const float* __restrict__ pq, float* __restrict__ stats) {
  const int c = blockIdx.x * 256 + threadIdx.x;
  float s = 0.f, q = 0.f;
  for (int i = 0; i < 32; ++i) {
    s += ps[i * 1024 + c];
    q += pq[i * 1024 + c];
  }
  const float mean = s * (1.f / 8192.f);
  const float var = q * (1.f / 8192.f) - mean * mean;
  stats[c] = mean;
  stats[1024 + c] = rsqrtf(fmaxf(var, 0.f) + 1e-5f);
}

__global__ __launch_bounds__(256) void bn_apply_kernel(
    const short* __restrict__ y, const float* __restrict__ g, const float* __restrict__ b,
    const float* __restrict__ stats, short* __restrict__ out) {
  const size_t i = (size_t)blockIdx.x * 256 + threadIdx.x;
  const size_t f = i << 2;
  const int c = (int)(f & 1023);
  const s4v yv = *reinterpret_cast<const s4v*>(&y[f]);
  s4v o;
#pragma unroll
  for (int j = 0; j < 4; ++j) {
    const float v = (bf2f(yv[j]) - stats[c + j]) * stats[1024 + c + j] * g[c + j] + b[c + j];
    o[j] = f2bf(v * sigmoid_(v));
  }
  *reinterpret_cast<s4v*>(&out[f]) = o;
}

// ---------------------------------------------------------------------------
extern "C" void kernel_launch(void* const* d_in, const int* in_sizes, int n_in,
                              void* d_out, int out_size, void* d_ws, size_t ws_size,
                              hipStream_t stream) {
  const float* x        = (const float*)d_in[0];
  const float* ffn1_w1  = (const float*)d_in[1];
  const float* ffn1_b1  = (const float*)d_in[2];
  const float* ffn1_w2  = (const float*)d_in[3];
  const float* ffn1_b2  = (const float*)d_in[4];
  const float* ln_att_g = (const float*)d_in[5];
  const float* ln_att_b = (const float*)d_in[6];
  const float* wq       = (const float*)d_in[7];
  const float* bq       = (const float*)d_in[8];
  const float* wk       = (const float*)d_in[9];
  const float* bk       = (const float*)d_in[10];
  const float* wv       = (const float*)d_in[11];
  const float* bv       = (const float*)d_in[12];
  const float* wo_      = (const float*)d_in[13];
  const float* bo       = (const float*)d_in[14];
  const float* cln_g    = (const float*)d_in[15];
  const float* cln_b    = (const float*)d_in[16];
  const float* pw1_w    = (const float*)d_in[17];
  const float* pw1_b    = (const float*)d_in[18];
  const float* dw_w     = (const float*)d_in[19];
  const float* dw_b     = (const float*)d_in[20];
  const float* bn_g     = (const float*)d_in[21];
  const float* bn_b     = (const float*)d_in[22];
  const float* pw2_w    = (const float*)d_in[23];
  const float* pw2_b    = (const float*)d_in[24];
  const float* ffn2_w1  = (const float*)d_in[25];
  const float* ffn2_b1  = (const float*)d_in[26];
  const float* ffn2_w2  = (const float*)d_in[27];
  const float* ffn2_b2  = (const float*)d_in[28];
  const float* ln_out_g = (const float*)d_in[29];
  const float* ln_out_b = (const float*)d_in[30];

  char* wsb = (char*)d_ws;
  const size_t MB = 1u << 20;
  short* buf_y = (short*)(wsb);            // residual stream bf16 (8 MB)
  char* Bre = wsb + 16 * MB;
  short* qkv16 = (short*)(Bre);            // q,k (B,H,T,64) + v^T (B,H,64,T'), 24 MB
  short* lnq  = (short*)(Bre + 48 * MB);
  short* ctx  = (short*)(Bre + 56 * MB);
  short* h1   = (short*)(Bre);
  short* xb   = (short*)(Bre + 16 * MB);
  short* gluo = (short*)(Bre);
  short* bno  = (short*)(Bre + 48 * MB);
  char* Cre = wsb + 80 * MB;
  short* lnc  = (short*)(Cre);
  short* dwo16= (short*)(Cre + 8 * MB);
  char* Dre = wsb + 112 * MB;
  short* w_f1w1 = (short*)(Dre);
  short* w_f1w2 = (short*)(Dre + 1 * MB);
  short* w_qkv  = (short*)(Dre + 2 * MB);
  short* w_wo   = (short*)(Dre + 3 * MB + 512 * 1024);
  short* w_pw1  = (short*)(Dre + 4 * MB);
  short* w_pw2  = (short*)(Dre + 6 * MB);
  short* w_f2w1 = (short*)(Dre + 7 * MB);
  short* w_f2w2 = (short*)(Dre + 8 * MB);
  float* bqkv   = (float*)(Dre + 9 * MB);
  float* ps     = (float*)(Dre + 9 * MB + 8192);
  float* pq     = (float*)(Dre + 10 * MB + 8192);
  float* stats  = (float*)(Dre + 11 * MB + 8192);
  float* rtbl   = (float*)(Dre + 12 * MB);

  const dim3 blk(256);

  // ---- single mega-prep
  prep_kernel<<<6022, blk, 0, stream>>>(
      x, xb, ffn1_w1, w_f1w1, ffn1_w2, w_f1w2, wq, wk, wv, w_qkv, wo_, w_wo,
      pw1_w, w_pw1, pw2_w, w_pw2, ffn2_w1, w_f2w1, ffn2_w2, w_f2w2,
      bq, bk, bv, bqkv, rtbl);

  // ---- FFN1: y = x + 0.5*(swish(x@w1+b1)@w2+b2)
  mgemm<64, 128, 64, 1, 512><<<dim3(8, 128), dim3(512), 0, stream>>>(xb, w_f1w1, ffn1_b1, nullptr, nullptr, h1, M_ROWS, 1024, 512);
  mgemm<64, 128, 64, 3, 512><<<dim3(4, 128), dim3(512), 0, stream>>>(h1, w_f1w2, ffn1_b2, nullptr, xb, buf_y, M_ROWS, 512, 1024);

  // ---- MHSA (QKV 8-wave with vstg aliased on smem; v stored k-permuted)
  ln_kernel<short><<<2048, blk, 0, stream>>>(buf_y, ln_att_g, ln_att_b, lnq);
  mgemm<128, 128, 32, 4, 512><<<dim3(12, 64), dim3(512), 0, stream>>>(lnq, w_qkv, bqkv, rtbl, nullptr, qkv16, M_ROWS, 1536, 512);
  attn_mfma_kernel<<<512, dim3(512), 0, stream>>>(qkv16, qkv16 + 4194304, qkv16 + 8388608, ctx);
  mgemm<64, 128, 64, 2, 512><<<dim3(4, 128), dim3(512), 0, stream>>>(ctx, w_wo, bo, nullptr, buf_y, buf_y, M_ROWS, 512, 512);

  // ---- Conv module (pw1 128x256; dwconv emits BN partial stats)
  ln_kernel<short><<<2048, blk, 0, stream>>>(buf_y, cln_g, cln_b, lnc);
  mgemm<128, 256, 32, 6, 512><<<dim3(8, 64), dim3(512), 0, stream>>>(lnc, w_pw1, pw1_b, nullptr, nullptr, gluo, M_ROWS, 2048, 512);
  dwconv_kernel<<<512, blk, 0, stream>>>(gluo, dw_w, dw_b, dwo16, ps, pq);
  bn_finalize_kernel<<<4, blk, 0, stream>>>(ps, pq, stats);
  bn_apply_kernel<<<8192, blk, 0, stream>>>(dwo16, bn_g, bn_b, stats, bno);
  mgemm<64, 128, 64, 2, 512><<<dim3(4, 128), dim3(512), 0, stream>>>(bno, w_pw2, pw2_b, nullptr, buf_y, buf_y, M_ROWS, 512, 1024);

  // ---- FFN2
  mgemm<64, 128, 64, 1, 512><<<dim3(8, 128), dim3(512), 0, stream>>>(buf_y, w_f2w1, ffn2_b1, nullptr, nullptr, h1, M_ROWS, 1024, 512);
  mgemm<64, 128, 64, 3, 512><<<dim3(4, 128), dim3(512), 0, stream>>>(h1, w_f2w2, ffn2_b2, nullptr, buf_y, buf_y, M_ROWS, 512, 1024);

  // ---- Final LN -> d_out (f32)
  ln_kernel<float><<<2048, blk, 0, stream>>>(buf_y, ln_out_g, ln_out_b, (float*)d_out);
}